// Round 4
// baseline (347.108 us; speedup 1.0000x reference)
//
#include <hip/hip_runtime.h>
#include <stdint.h>
#include <math.h>

// MultiGeometryAttention — f32 in/out. B=2 T=2048 C=1024 H=16 HD=64.
// heads 0-5 sdpa(0.125) | 6-9 hyperbolic(curvature) | 10-15 cos-normalized sdpa(8).
// R13 (360->316us): 2-PRODUCT everywhere. GEMMs: x*W ~= (x_hi+x_lo)*W_hi via
// A'=[hi|lo], B'=[hi|hi], K'=2K. Attention: 2-product scores, K2 hi-only (8MB).
// Softmax: sscale*log2e folded into q (geom0/2), no Moff. bh-major block order.
// R14 (FAILED, 486us): __launch_bounds__(256,4) -> VGPR 64 + massive spills.
// R15 (313us): (256,2) fixed spills; occupancy stuck ~13% regardless of WG shape.
// R16 (287us): hoisted all 16 K/V loads per ktile into registers -> attn_part
// 117->88us (MfmaUtil 9.6->12.9, VALU 31->42). Still ~6,650 cyc/ktile vs ~1,500
// issue floor: K-loads issued at iter top, consumed ~immediately -> one exposed
// L2 round trip per ktile + wait-serialized chains.
// R17: cross-ktile pipeline. K double-buffered (kfA/kfB ping-pong, 2 parity
// arms, static indexing); per iter issue V_cur -> tk_cur -> K_next so PV waits
// vmcnt(8) (K_next stays in flight) and next QK finds K complete. +32 VGPR
// (~156 arch, no spill). Predict attn_part 88 -> ~68us, FETCH unchanged.
// WS (proven peak 94,896,128 B):
//  phase1: AX[0,16777216) BW[16777216,29360128) | QKVF[33554432,83886080)
//  post-prep: Q2[0,16777216) K2hi[16777216,25165824) V2[25165824,33554432)
//             PART[33554432,76808192) BPW[76808192,81002496)
//  post-attn: AY[0,16777216) | QQ[94371840) KK[94633984)

typedef __bf16 bf16x8 __attribute__((ext_vector_type(8)));
typedef float f32x4 __attribute__((ext_vector_type(4)));

static __device__ __forceinline__ float bf2f(unsigned short u) {
  union { unsigned int i; float f; } v; v.i = ((unsigned int)u) << 16; return v.f;
}
static __device__ __forceinline__ unsigned short f2bf(float f) {
  union { float f; unsigned int i; } v; v.f = f;
  unsigned int x = v.i;
  x += 0x7fffu + ((x >> 16) & 1u);   // RNE
  return (unsigned short)(x >> 16);
}

// direct global->LDS async copy, 16B/lane (gemm staging only).
static __device__ __forceinline__ void async_copy16(const void* gsrc, void* ldst) {
  auto* lp = reinterpret_cast<__attribute__((address_space(3))) unsigned int*>(
      reinterpret_cast<uintptr_t>(ldst));
  auto* gp = reinterpret_cast<const __attribute__((address_space(1))) unsigned int*>(
      reinterpret_cast<uintptr_t>(gsrc));
  __builtin_amdgcn_global_load_lds(gp, lp, 16, 0, 0);
}

// f32 [rows][1024] -> split bf16 [rows][2048]. PAT=0 (A): [hi|lo]; PAT=1 (B): [hi|hi].
template <int PAT>
__global__ __launch_bounds__(256) void split2(const float* __restrict__ in,
                                              unsigned short* __restrict__ out) {
  const int row = blockIdx.x;
  const int kq = threadIdx.x * 4;
  const f32x4 x = *(const f32x4*)(in + (size_t)row * 1024 + kq);
  unsigned short hi[4], lo[4];
#pragma unroll
  for (int i = 0; i < 4; ++i) {
    hi[i] = f2bf(x[i]);
    lo[i] = f2bf(x[i] - bf2f(hi[i]));   // exact residual in f32
  }
  uint2 uh, ul;
  uh.x = (unsigned)hi[0] | ((unsigned)hi[1] << 16);
  uh.y = (unsigned)hi[2] | ((unsigned)hi[3] << 16);
  ul.x = (unsigned)lo[0] | ((unsigned)lo[1] << 16);
  ul.y = (unsigned)lo[2] | ((unsigned)lo[3] << 16);
  unsigned short* op = out + (size_t)row * 2048 + kq;
  *(uint2*)(op)        = uh;
  *(uint2*)(op + 1024) = PAT ? uh : ul;
}

// C[m][n] = sum_k A[m][k]*B[n][k] (+bias[n]) -> f32. 128x128 tile, BK=64, 4 waves,
// 16x16x32 bf16 MFMA, XOR-swizzled LDS (verified).
template <int HASBIAS>
__global__ __launch_bounds__(256) void gemm_bt(
    const unsigned short* __restrict__ A, const unsigned short* __restrict__ Bm,
    float* __restrict__ C, const float* __restrict__ bias, int N_, int K_) {
  alignas(16) __shared__ unsigned short smA[128 * 64];
  alignas(16) __shared__ unsigned short smB[128 * 64];
  const int tid = threadIdx.x;
  const int lane = tid & 63;
  const int wv = tid >> 6;
  const int wm = wv >> 1, wn = wv & 1;
  const long m0 = (long)blockIdx.y * 128, n0 = (long)blockIdx.x * 128;

  const f32x4 zero4 = {0.f, 0.f, 0.f, 0.f};
  f32x4 acc[4][4];
#pragma unroll
  for (int i = 0; i < 4; ++i)
#pragma unroll
    for (int j = 0; j < 4; ++j) acc[i][j] = zero4;

  int mrow[4], gg[4];
#pragma unroll
  for (int w = 0; w < 4; ++w) {
    int c = w * 256 + tid;
    mrow[w] = c >> 3;
    gg[w] = (c & 7) ^ ((c >> 3) & 7);
  }

  const int kTiles = K_ >> 6;
  for (int kt = 0; kt < kTiles; ++kt) {
    if (kt) __syncthreads();
    const int kb = kt << 6;
#pragma unroll
    for (int w = 0; w < 4; ++w) {
      const int c = w * 256 + tid;
      async_copy16(A + (size_t)(m0 + mrow[w]) * K_ + kb + gg[w] * 8,
                   (char*)smA + c * 16);
      async_copy16(Bm + (size_t)(n0 + mrow[w]) * K_ + kb + gg[w] * 8,
                   (char*)smB + c * 16);
    }
    __syncthreads();
#pragma unroll
    for (int ks = 0; ks < 2; ++ks) {
      bf16x8 af[4], bg[4];
#pragma unroll
      for (int i = 0; i < 4; ++i) {
        const int ra = wm * 64 + i * 16 + (lane & 15);
        const int ga = (ks * 4 + (lane >> 4)) ^ (ra & 7);
        af[i] = *(const bf16x8*)((const char*)smA + ra * 128 + ga * 16);
        const int rb = wn * 64 + i * 16 + (lane & 15);
        const int gb2 = (ks * 4 + (lane >> 4)) ^ (rb & 7);
        bg[i] = *(const bf16x8*)((const char*)smB + rb * 128 + gb2 * 16);
      }
#pragma unroll
      for (int i = 0; i < 4; ++i)
#pragma unroll
        for (int j = 0; j < 4; ++j)
          acc[i][j] = __builtin_amdgcn_mfma_f32_16x16x32_bf16(af[i], bg[j], acc[i][j], 0, 0, 0);
    }
  }

  const int r0 = wm * 64 + (lane >> 4) * 4;
  const int c0 = wn * 64 + (lane & 15);
#pragma unroll
  for (int j = 0; j < 4; ++j) {
    const long col = n0 + c0 + j * 16;
    float bv = 0.f;
    if (HASBIAS) bv = bias[col];
#pragma unroll
    for (int i = 0; i < 4; ++i) {
#pragma unroll
      for (int r = 0; r < 4; ++r) {
        const long row = m0 + r0 + i * 16 + r;
        C[row * N_ + col] = acc[i][j][r] + bv;
      }
    }
  }
}

// prep: rotary q,k; norms; normalize h>=10; fold sscale*log2e into q (geom0/2);
// emit fragment-linear tiles. Q2: [hi|lo] 8 frags/qw. K2: hi-only 8 frags/ktile.
// V2: 8 frags/ktile.
__global__ __launch_bounds__(256) void prep(
    const float* __restrict__ qkvf, unsigned short* __restrict__ Q2,
    unsigned short* __restrict__ K2, unsigned short* __restrict__ V2,
    float* __restrict__ qq, float* __restrict__ kk, const float* __restrict__ curvg) {
  __shared__ unsigned short Vl[64 * 66];
  const int tid = threadIdx.x;
  const int zz = blockIdx.x;
  const int ttile = zz & 31, bh = zz >> 5;
  const int b = bh >> 4, h = bh & 15;
  const int t0 = ttile * 64;
  const int tr = tid >> 2, seg = tid & 3;
  const int t = t0 + tr;
  const float* src = qkvf + ((size_t)(b * 2048 + t)) * 3072 + h * 64 + seg * 16;

  float qv[16], kv[16], vv[16];
#pragma unroll
  for (int c = 0; c < 4; ++c) {
    const f32x4 a  = *(const f32x4*)(src + c * 4);
    const f32x4 bb = *(const f32x4*)(src + 1024 + c * 4);
    const f32x4 cc = *(const f32x4*)(src + 2048 + c * 4);
#pragma unroll
    for (int e = 0; e < 4; ++e) { qv[c*4+e] = a[e]; kv[c*4+e] = bb[e]; vv[c*4+e] = cc[e]; }
  }
  float qr[16], kr[16];
#pragma unroll
  for (int e = 0; e < 16; ++e) {
    const int d = seg * 16 + e;
    const int i = d & 31;
    const float invf = exp2f(-0.41524101186109286f * (float)i);  // 10000^(-i/32)
    float sn, cs;
    sincosf((float)t * invf, &sn, &cs);
    const float qo = __shfl_xor(qv[e], 2, 64);
    const float ko = __shfl_xor(kv[e], 2, 64);
    qr[e] = (d < 32) ? (qv[e] * cs + qo * sn) : (qv[e] * cs - qo * sn);
    kr[e] = (d < 32) ? (kv[e] * cs + ko * sn) : (kv[e] * cs - ko * sn);
  }
  float sq = 0.f, sk = 0.f;
#pragma unroll
  for (int e = 0; e < 16; ++e) { sq += qr[e] * qr[e]; sk += kr[e] * kr[e]; }
  sq += __shfl_xor(sq, 1, 64); sq += __shfl_xor(sq, 2, 64);
  sk += __shfl_xor(sk, 1, 64); sk += __shfl_xor(sk, 2, 64);
  float qscale = 0.125f * 1.4426950408889634f;   // geom0: fold sscale*log2e
  if (h >= 10) {
    const float rq = 1.0f / fmaxf(sqrtf(sq), 1e-12f);
    const float rk = 1.0f / fmaxf(sqrtf(sk), 1e-12f);
#pragma unroll
    for (int e = 0; e < 16; ++e) { qr[e] *= rq; kr[e] *= rk; }
    qscale = 8.0f * 1.4426950408889634f;         // geom2
  } else if (h >= 6) {
    qscale = 1.0f;                                // geom1: raw dot needed
  }
#pragma unroll
  for (int e = 0; e < 16; ++e) qr[e] *= qscale;
  if (seg == 0) {
    const int idx = b * 32768 + h * 2048 + t;
    float oq = sq, ok = sk;
    if (h >= 6 && h < 10) {
      const float invc = 1.0f / curvg[h - 6];
      oq = sqrtf(invc + sq);
      ok = sqrtf(invc + sk);
    }
    qq[idx] = oq;
    kk[idx] = ok;
  }
  const int st = seg >> 1;
  const int quadA = (seg * 2) & 3, quadB = (seg * 2 + 1) & 3;
  {
    unsigned int wh[8], wl[8];
#pragma unroll
    for (int p = 0; p < 8; ++p) {
      unsigned short h0 = f2bf(qr[2*p]), h1 = f2bf(qr[2*p+1]);
      unsigned short l0 = f2bf(qr[2*p] - bf2f(h0)), l1 = f2bf(qr[2*p+1] - bf2f(h1));
      wh[p] = (unsigned)h0 | ((unsigned)h1 << 16);
      wl[p] = (unsigned)l0 | ((unsigned)l1 << 16);
    }
    const int qi = (t >> 4) & 1, c15q = t & 15;
    unsigned short* qs = Q2 + ((size_t)bh * 64 + (t >> 5)) * 4096;
    const int fh = ((qi * 2 + st) * 2 + 0) * 512, fl = fh + 512;
    *(uint4*)(qs + fh + quadA * 128 + c15q * 8) = uint4{wh[0], wh[1], wh[2], wh[3]};
    *(uint4*)(qs + fh + quadB * 128 + c15q * 8) = uint4{wh[4], wh[5], wh[6], wh[7]};
    *(uint4*)(qs + fl + quadA * 128 + c15q * 8) = uint4{wl[0], wl[1], wl[2], wl[3]};
    *(uint4*)(qs + fl + quadB * 128 + c15q * 8) = uint4{wl[4], wl[5], wl[6], wl[7]};
    // K: hi frags only
#pragma unroll
    for (int p = 0; p < 8; ++p) {
      unsigned short h0 = f2bf(kr[2*p]), h1 = f2bf(kr[2*p+1]);
      wh[p] = (unsigned)h0 | ((unsigned)h1 << 16);
    }
    const int kj = (tr >> 4) & 3, c15k = tr & 15;
    unsigned short* ks = K2 + ((size_t)bh * 32 + ttile) * 4096;
    const int gh = (st * 4 + kj) * 512;
    *(uint4*)(ks + gh + quadA * 128 + c15k * 8) = uint4{wh[0], wh[1], wh[2], wh[3]};
    *(uint4*)(ks + gh + quadB * 128 + c15k * 8) = uint4{wh[4], wh[5], wh[6], wh[7]};
  }
#pragma unroll
  for (int e = 0; e < 16; ++e) Vl[(seg * 16 + e) * 66 + tr] = f2bf(vv[e]);
  __syncthreads();
  {
    const int d = tid >> 2, tch = (tid & 3) * 16;
    unsigned int wv2[8];
#pragma unroll
    for (int p = 0; p < 8; ++p) {
      const unsigned short a0 = Vl[d * 66 + tch + 2*p];
      const unsigned short a1 = Vl[d * 66 + tch + 2*p + 1];
      wv2[p] = (unsigned)a0 | ((unsigned)a1 << 16);
    }
    const int dj = d >> 4, c15v = d & 15;
    const int ks2 = tch >> 5;
    const int qvA = (tch >> 3) & 3, qvB = ((tch >> 3) + 1) & 3;
    unsigned short* vs = V2 + ((size_t)bh * 32 + ttile) * 4096 + (ks2 * 4 + dj) * 512;
    *(uint4*)(vs + qvA * 128 + c15v * 8) = uint4{wv2[0], wv2[1], wv2[2], wv2[3]};
    *(uint4*)(vs + qvB * 128 + c15v * 8) = uint4{wv2[4], wv2[5], wv2[6], wv2[7]};
  }
}

// Split-K barrier-free MFMA flash attention. 2-product scores; geom0/2 scale folded
// into q -> p = exp2(s), no Moff. bh-major block order. 4 independent waves/WG.
// R17: cross-ktile pipeline — K double-buffered (kfA/kfB parity ping-pong);
// per-iter issue order V_cur -> tk_cur -> K_next keeps vmcnt waits counted
// (PV waits vmcnt(8), QK finds K complete from prev iter).
__global__ __launch_bounds__(256, 2) void attn_part(
    const unsigned short* __restrict__ Q2, const unsigned short* __restrict__ K2,
    const unsigned short* __restrict__ V2, const float* __restrict__ tqq,
    const float* __restrict__ tkk, const float* __restrict__ curvg,
    float* __restrict__ part) {
  alignas(16) __shared__ unsigned short Pl[4][32 * 64];  // 4x 4KB wave-private P tiles
  const int tid = threadIdx.x;
  const int lane = tid & 63;
  const int wv = tid >> 6;
  unsigned short* Pw = &Pl[wv][0];
  const int quad = lane >> 4, c15 = lane & 15;
  const int z = blockIdx.x * 4 + wv;
  const int bh = z / 160;                // bh-major
  const int u = 159 - (z - bh * 160);    // big (qw,ch) first within the head
  int qw, ch;
  if (u < 16)      { qw = u; ch = 0; }
  else if (u < 48) { qw = 16 + ((u - 16) >> 1); ch = (u - 16) & 1; }
  else if (u < 96) { const int s2 = u - 48; const int q3 = s2 / 3; qw = 32 + q3; ch = s2 - 3 * q3; }
  else             { const int s2 = u - 96; qw = 48 + (s2 >> 2); ch = s2 & 3; }
  const int h = bh & 15;
  const int geom = (h < 6) ? 0 : ((h < 10) ? 1 : 2);
  const int qrow0 = qw * 32;
  const f32x4 zero4 = {0.f, 0.f, 0.f, 0.f};

  const unsigned short* qbase = Q2 + ((size_t)bh * 64 + qw) * 4096;
  bf16x8 qh[2][2], ql[2][2];
#pragma unroll
  for (int qi = 0; qi < 2; ++qi)
#pragma unroll
    for (int st = 0; st < 2; ++st) {
      const int f = ((qi * 2 + st) * 2) * 512 + lane * 8;
      qh[qi][st] = *(const bf16x8*)(qbase + f);
      ql[qi][st] = *(const bf16x8*)(qbase + f + 512);
    }

  float curv = 1.f, sic = 1.f;
  const float Moff = 4.0f;               // geom1 only
  f32x4 tq4[2] = {zero4, zero4};
  if (geom == 1) {
    curv = curvg[h - 6];
    sic = sqrtf(1.0f / curv);
#pragma unroll
    for (int qi = 0; qi < 2; ++qi)
      tq4[qi] = *(const f32x4*)(tqq + bh * 2048 + qrow0 + qi * 16 + quad * 4);
  }

  const __bf16 one_b = (__bf16)1.0f;
  const bf16x8 ones = {one_b, one_b, one_b, one_b, one_b, one_b, one_b, one_b};

  f32x4 o[2][4];
  f32x4 ol[2] = {zero4, zero4};
#pragma unroll
  for (int qi = 0; qi < 2; ++qi)
#pragma unroll
    for (int dj = 0; dj < 4; ++dj) o[qi][dj] = zero4;

  const int nkt = (qw >> 1) + 1;
  const int ktB = ch * 8;
  const int ktE = (ktB + 8 < nkt) ? (ktB + 8) : nkt;

  bf16x8 kfA[2][4], kfB[2][4];   // double-buffered K fragments
  bf16x8 vf[2][4];               // single-buffered V (latency covered by QK+softmax)
  float tkf[4];

#define STAGE_V_TK(KT) do {                                                   \
    const unsigned short* vb_ = V2 + ((size_t)bh * 32 + (KT)) * 4096;         \
    _Pragma("unroll")                                                         \
    for (int ks2 = 0; ks2 < 2; ++ks2)                                         \
      _Pragma("unroll")                                                       \
      for (int dj = 0; dj < 4; ++dj)                                          \
        vf[ks2][dj] = *(const bf16x8*)(vb_ + (ks2 * 4 + dj) * 512 + lane * 8);\
    if (geom == 1) {                                                          \
      _Pragma("unroll")                                                       \
      for (int kj = 0; kj < 4; ++kj)                                          \
        tkf[kj] = tkk[bh * 2048 + (KT) * 64 + kj * 16 + c15];                 \
    }                                                                         \
  } while (0)

#define STAGE_K(KF, KT) do {                                                  \
    const unsigned short* kb_ = K2 + ((size_t)bh * 32 + (KT)) * 4096;         \
    _Pragma("unroll")                                                         \
    for (int st = 0; st < 2; ++st)                                            \
      _Pragma("unroll")                                                       \
      for (int kj = 0; kj < 4; ++kj)                                          \
        KF[st][kj] = *(const bf16x8*)(kb_ + (st * 4 + kj) * 512 + lane * 8);  \
  } while (0)

#define KTILE_COMPUTE(KF, KT) do {                                            \
    const int kb = (KT) * 64;                                                 \
    f32x4 s[2][4];                                                            \
    _Pragma("unroll")                                                         \
    for (int qi = 0; qi < 2; ++qi)                                            \
      _Pragma("unroll")                                                       \
      for (int kj = 0; kj < 4; ++kj) s[qi][kj] = zero4;                       \
    __builtin_amdgcn_s_setprio(1);                                            \
    _Pragma("unroll")                                                         \
    for (int st = 0; st < 2; ++st) {                                          \
      _Pragma("unroll")                                                       \
      for (int kj = 0; kj < 4; ++kj) {                                        \
        _Pragma("unroll")                                                     \
        for (int qi = 0; qi < 2; ++qi) {                                      \
          s[qi][kj] = __builtin_amdgcn_mfma_f32_16x16x32_bf16(qh[qi][st], KF[st][kj], s[qi][kj], 0, 0, 0); \
          s[qi][kj] = __builtin_amdgcn_mfma_f32_16x16x32_bf16(ql[qi][st], KF[st][kj], s[qi][kj], 0, 0, 0); \
        }                                                                     \
      }                                                                       \
    }                                                                         \
    __builtin_amdgcn_s_setprio(0);                                            \
    const bool needmask = ((KT) == nkt - 1);                                  \
    _Pragma("unroll")                                                         \
    for (int qi = 0; qi < 2; ++qi) {                                          \
      const int qbaserow = qrow0 + qi * 16 + quad * 4;                        \
      _Pragma("unroll")                                                       \
      for (int kj = 0; kj < 4; ++kj) {                                        \
        const int skey = kj * 16 + c15;                                       \
        const int key = kb + skey;                                            \
        const f32x4 d4 = s[qi][kj];                                           \
        f32x4 p;                                                              \
        if (geom == 1) {                                                      \
          const float tk = tkf[kj];                                           \
          _Pragma("unroll")                                                   \
          for (int r = 0; r < 4; ++r) {                                       \
            const float a = fmaxf(curv * (tq4[qi][r] * tk - d4[r]), 1.0f + 1e-7f); \
            const float dis = sic * __logf(a + sqrtf(a * a - 1.0f));          \
            p[r] = __expf(__builtin_amdgcn_rcpf(1e-6f + dis) - Moff);         \
          }                                                                   \
        } else {                                                              \
          _Pragma("unroll")                                                   \
          for (int r = 0; r < 4; ++r) p[r] = exp2f(d4[r]);                    \
        }                                                                     \
        if (needmask) {                                                       \
          _Pragma("unroll")                                                   \
          for (int r = 0; r < 4; ++r)                                         \
            if (key > qbaserow + r) p[r] = 0.0f;                              \
        }                                                                     \
        _Pragma("unroll")                                                     \
        for (int r = 0; r < 4; ++r) {                                         \
          union { float f; unsigned u2; } pv; pv.f = p[r];                    \
          const int row = qi * 16 + quad * 4 + r;                             \
          const int g = (skey >> 3) ^ (row & 7);                              \
          Pw[row * 64 + g * 8 + (skey & 7)] = (unsigned short)(pv.u2 >> 16);  \
        }                                                                     \
      }                                                                       \
    }                                                                         \
    __builtin_amdgcn_s_setprio(1);                                            \
    _Pragma("unroll")                                                         \
    for (int ks2 = 0; ks2 < 2; ++ks2) {                                       \
      bf16x8 av[2];                                                           \
      _Pragma("unroll")                                                       \
      for (int qi = 0; qi < 2; ++qi) {                                        \
        const int m = qi * 16 + c15;                                          \
        const int g = (ks2 * 4 + quad) ^ (m & 7);                             \
        av[qi] = *(const bf16x8*)(Pw + m * 64 + g * 8);                       \
        ol[qi] = __builtin_amdgcn_mfma_f32_16x16x32_bf16(av[qi], ones, ol[qi], 0, 0, 0); \
      }                                                                       \
      _Pragma("unroll")                                                       \
      for (int dj = 0; dj < 4; ++dj) {                                        \
        _Pragma("unroll")                                                     \
        for (int qi = 0; qi < 2; ++qi)                                        \
          o[qi][dj] = __builtin_amdgcn_mfma_f32_16x16x32_bf16(av[qi], vf[ks2][dj], o[qi][dj], 0, 0, 0); \
      }                                                                       \
    }                                                                         \
    __builtin_amdgcn_s_setprio(0);                                            \
  } while (0)

  STAGE_K(kfA, ktB);
  for (int kt = ktB; kt < ktE; ++kt) {
    const int nx = (kt + 1 < ktE) ? kt + 1 : kt;   // clamped: last prefetch is dead
    if ((kt - ktB) & 1) {
      STAGE_V_TK(kt);
      STAGE_K(kfA, nx);
      KTILE_COMPUTE(kfB, kt);
    } else {
      STAGE_V_TK(kt);
      STAGE_K(kfB, nx);
      KTILE_COMPUTE(kfA, kt);
    }
  }

#undef STAGE_V_TK
#undef STAGE_K
#undef KTILE_COMPUTE

  // ---- partial write: slot = bh*160 + u, stride 2112 f32
  float* slot = part + (size_t)(bh * 160 + u) * 2112;
#pragma unroll
  for (int qi = 0; qi < 2; ++qi)
#pragma unroll
    for (int dj = 0; dj < 4; ++dj)
      *(f32x4*)(slot + (qi * 4 + dj) * 256 + lane * 4) = o[qi][dj];
  if (c15 == 0) {
#pragma unroll
    for (int qi = 0; qi < 2; ++qi)
      *(f32x4*)(slot + 2048 + qi * 16 + quad * 4) = ol[qi];
  }
}

// Sum chunk partials, divide, LDS-transpose, write A'y [hi|lo] (2048-wide).
// 4 waves per WG, wave-private Ol slice.
__global__ __launch_bounds__(256) void attn_reduce(
    const float* __restrict__ part, unsigned short* __restrict__ Ay) {
  __shared__ float Ol[4][32 * 65];
  const int tid = threadIdx.x;
  const int lane = tid & 63;
  const int wv = tid >> 6;
  float* Olw = &Ol[wv][0];
  const int quad = lane >> 4, c15 = lane & 15;
  const int z = blockIdx.x * 4 + wv, bh = z & 31, qw = 63 - (z >> 5);
  const int b = bh >> 4, h = bh & 15;
  const int G = qw >> 4;
  const int base = qw + 8 * G * (G - 1) + (qw & 15) * G;
  const float* slot0 = part + (size_t)(bh * 160 + base) * 2112;

  const f32x4 zero4 = {0.f, 0.f, 0.f, 0.f};
  f32x4 o[8];
  f32x4 l4[2] = {zero4, zero4};
#pragma unroll
  for (int i = 0; i < 8; ++i) o[i] = zero4;
  for (int chv = 0; chv <= G; ++chv) {
    const float* sl = slot0 + chv * 2112;
#pragma unroll
    for (int i = 0; i < 8; ++i) o[i] += *(const f32x4*)(sl + i * 256 + lane * 4);
#pragma unroll
    for (int qi = 0; qi < 2; ++qi)
      l4[qi] += *(const f32x4*)(sl + 2048 + qi * 16 + quad * 4);
  }
#pragma unroll
  for (int qi = 0; qi < 2; ++qi) {
    f32x4 invl;
#pragma unroll
    for (int r = 0; r < 4; ++r) invl[r] = __builtin_amdgcn_rcpf(l4[qi][r]);
#pragma unroll
    for (int dj = 0; dj < 4; ++dj) {
      const f32x4 val = o[qi * 4 + dj] * invl;
#pragma unroll
      for (int r = 0; r < 4; ++r)
        Olw[(qi * 16 + quad * 4 + r) * 65 + dj * 16 + c15] = val[r];
    }
  }
  __syncthreads();
  const int row = lane >> 1, half = lane & 1;
  const float* rp = Olw + row * 65 + half * 32;
  unsigned int uh[16], ul2[16];
#pragma unroll
  for (int p = 0; p < 16; ++p) {
    const float v0 = rp[2 * p], v1 = rp[2 * p + 1];
    const unsigned short h0 = f2bf(v0), h1 = f2bf(v1);
    const unsigned short g0 = f2bf(v0 - bf2f(h0)), g1 = f2bf(v1 - bf2f(h1));
    uh[p] = (unsigned)h0 | ((unsigned)h1 << 16);
    ul2[p] = (unsigned)g0 | ((unsigned)g1 << 16);
  }
  unsigned short* yp = Ay + ((size_t)(b * 2048 + qw * 32 + row)) * 2048 + h * 64 + half * 32;
#pragma unroll
  for (int c = 0; c < 4; ++c) {
    *(uint4*)(yp + 8 * c)        = uint4{uh[4*c], uh[4*c+1], uh[4*c+2], uh[4*c+3]};
    *(uint4*)(yp + 1024 + 8 * c) = uint4{ul2[4*c], ul2[4*c+1], ul2[4*c+2], ul2[4*c+3]};
  }
}

extern "C" void kernel_launch(void* const* d_in, const int* in_sizes, int n_in,
                              void* d_out, int out_size, void* d_ws, size_t ws_size,
                              hipStream_t stream) {
  const float* x      = (const float*)d_in[0];
  const float* qkv_w  = (const float*)d_in[1];
  const float* proj_w = (const float*)d_in[2];
  const float* proj_b = (const float*)d_in[3];
  const float* curvature = (const float*)d_in[4];
  float* out = (float*)d_out;

  char* ws = (char*)d_ws;
  unsigned short* AX   = (unsigned short*)ws;                     // 4096x2048 bf16
  unsigned short* BW   = (unsigned short*)(ws + 16777216);        // 3072x2048 bf16
  float*          QKVF = (float*)(ws + 33554432);                 // 4096x3072 f32
  unsigned short* Q2   = (unsigned short*)ws;                     // 16MB
  unsigned short* K2   = (unsigned short*)(ws + 16777216);        // 8MB (hi-only)
  unsigned short* V2   = (unsigned short*)(ws + 25165824);        // 8MB
  float*          PART = (float*)(ws + 33554432);                 // 43,253,760 B
  unsigned short* BPW  = (unsigned short*)(ws + 76808192);        // 1024x2048 bf16
  unsigned short* AY   = (unsigned short*)ws;                     // 4096x2048 bf16
  float*          QQ   = (float*)(ws + 94371840);
  float*          KK   = (float*)(ws + 94633984);

  split2<0><<<4096, 256, 0, stream>>>(x, AX);
  split2<1><<<3072, 256, 0, stream>>>(qkv_w, BW);

  gemm_bt<0><<<dim3(24, 32), 256, 0, stream>>>(AX, BW, QKVF, nullptr, 3072, 2048);

  prep<<<1024, 256, 0, stream>>>(QKVF, Q2, K2, V2, QQ, KK, curvature);

  split2<1><<<1024, 256, 0, stream>>>(proj_w, BPW);   // after prep: QKVF region free

  attn_part<<<1280, 256, 0, stream>>>(Q2, K2, V2, QQ, KK, curvature, PART);

  attn_reduce<<<512, 256, 0, stream>>>(PART, AY);

  gemm_bt<1><<<dim3(8, 32), 256, 0, stream>>>(AY, BPW, out, proj_b, 1024, 2048);
}

// Round 5
// 326.618 us; speedup vs baseline: 1.0627x; 1.0627x over previous
//
#include <hip/hip_runtime.h>
#include <stdint.h>
#include <math.h>

// MultiGeometryAttention — f32 in/out. B=2 T=2048 C=1024 H=16 HD=64.
// heads 0-5 sdpa(0.125) | 6-9 hyperbolic(curvature) | 10-15 cos-normalized sdpa(8).
// R13 (360->316us): 2-PRODUCT everywhere. GEMMs: x*W ~= (x_hi+x_lo)*W_hi via
// A'=[hi|lo], B'=[hi|hi], K'=2K. Attention: 2-product scores, K2 hi-only (8MB).
// Softmax: sscale*log2e folded into q (geom0/2), no Moff. bh-major block order.
// R14 (FAILED, 486us): __launch_bounds__(256,4) -> VGPR 64 + massive spills.
// R15 (313us): (256,2) fixed spills; occupancy stuck ~13% regardless of WG shape.
// R16 (287us): per-ktile K/V load batch into registers -> attn_part 117->88us.
// R17 (FAILED, 347us): K dbuf with STAGE_K(next) BEFORE compute + (256,2):
// peak live ~220, allocator clamped 128 + spilled (WRITE 41.6->78.7MB).
// R18: same K dbuf but STAGE_K(next) issued AFTER the QK block (kf_cur dead
// there -> buffer lifetimes barely overlap, peak ~190) and __launch_bounds__
// (256,1) (cap 512 — allocator free to take ~190; measured residency was
// ~1 wave/EU at every VGPR level so the relaxed floor costs nothing).
// Tripwire: FETCH ~73MB / WRITE ~41.6MB means no spill; else revert to R16.
// WS (proven peak 94,896,128 B):
//  phase1: AX[0,16777216) BW[16777216,29360128) | QKVF[33554432,83886080)
//  post-prep: Q2[0,16777216) K2hi[16777216,25165824) V2[25165824,33554432)
//             PART[33554432,76808192) BPW[76808192,81002496)
//  post-attn: AY[0,16777216) | QQ[94371840) KK[94633984)

typedef __bf16 bf16x8 __attribute__((ext_vector_type(8)));
typedef float f32x4 __attribute__((ext_vector_type(4)));

static __device__ __forceinline__ float bf2f(unsigned short u) {
  union { unsigned int i; float f; } v; v.i = ((unsigned int)u) << 16; return v.f;
}
static __device__ __forceinline__ unsigned short f2bf(float f) {
  union { float f; unsigned int i; } v; v.f = f;
  unsigned int x = v.i;
  x += 0x7fffu + ((x >> 16) & 1u);   // RNE
  return (unsigned short)(x >> 16);
}

// direct global->LDS async copy, 16B/lane (gemm staging only).
static __device__ __forceinline__ void async_copy16(const void* gsrc, void* ldst) {
  auto* lp = reinterpret_cast<__attribute__((address_space(3))) unsigned int*>(
      reinterpret_cast<uintptr_t>(ldst));
  auto* gp = reinterpret_cast<const __attribute__((address_space(1))) unsigned int*>(
      reinterpret_cast<uintptr_t>(gsrc));
  __builtin_amdgcn_global_load_lds(gp, lp, 16, 0, 0);
}

// f32 [rows][1024] -> split bf16 [rows][2048]. PAT=0 (A): [hi|lo]; PAT=1 (B): [hi|hi].
template <int PAT>
__global__ __launch_bounds__(256) void split2(const float* __restrict__ in,
                                              unsigned short* __restrict__ out) {
  const int row = blockIdx.x;
  const int kq = threadIdx.x * 4;
  const f32x4 x = *(const f32x4*)(in + (size_t)row * 1024 + kq);
  unsigned short hi[4], lo[4];
#pragma unroll
  for (int i = 0; i < 4; ++i) {
    hi[i] = f2bf(x[i]);
    lo[i] = f2bf(x[i] - bf2f(hi[i]));   // exact residual in f32
  }
  uint2 uh, ul;
  uh.x = (unsigned)hi[0] | ((unsigned)hi[1] << 16);
  uh.y = (unsigned)hi[2] | ((unsigned)hi[3] << 16);
  ul.x = (unsigned)lo[0] | ((unsigned)lo[1] << 16);
  ul.y = (unsigned)lo[2] | ((unsigned)lo[3] << 16);
  unsigned short* op = out + (size_t)row * 2048 + kq;
  *(uint2*)(op)        = uh;
  *(uint2*)(op + 1024) = PAT ? uh : ul;
}

// C[m][n] = sum_k A[m][k]*B[n][k] (+bias[n]) -> f32. 128x128 tile, BK=64, 4 waves,
// 16x16x32 bf16 MFMA, XOR-swizzled LDS (verified).
template <int HASBIAS>
__global__ __launch_bounds__(256) void gemm_bt(
    const unsigned short* __restrict__ A, const unsigned short* __restrict__ Bm,
    float* __restrict__ C, const float* __restrict__ bias, int N_, int K_) {
  alignas(16) __shared__ unsigned short smA[128 * 64];
  alignas(16) __shared__ unsigned short smB[128 * 64];
  const int tid = threadIdx.x;
  const int lane = tid & 63;
  const int wv = tid >> 6;
  const int wm = wv >> 1, wn = wv & 1;
  const long m0 = (long)blockIdx.y * 128, n0 = (long)blockIdx.x * 128;

  const f32x4 zero4 = {0.f, 0.f, 0.f, 0.f};
  f32x4 acc[4][4];
#pragma unroll
  for (int i = 0; i < 4; ++i)
#pragma unroll
    for (int j = 0; j < 4; ++j) acc[i][j] = zero4;

  int mrow[4], gg[4];
#pragma unroll
  for (int w = 0; w < 4; ++w) {
    int c = w * 256 + tid;
    mrow[w] = c >> 3;
    gg[w] = (c & 7) ^ ((c >> 3) & 7);
  }

  const int kTiles = K_ >> 6;
  for (int kt = 0; kt < kTiles; ++kt) {
    if (kt) __syncthreads();
    const int kb = kt << 6;
#pragma unroll
    for (int w = 0; w < 4; ++w) {
      const int c = w * 256 + tid;
      async_copy16(A + (size_t)(m0 + mrow[w]) * K_ + kb + gg[w] * 8,
                   (char*)smA + c * 16);
      async_copy16(Bm + (size_t)(n0 + mrow[w]) * K_ + kb + gg[w] * 8,
                   (char*)smB + c * 16);
    }
    __syncthreads();
#pragma unroll
    for (int ks = 0; ks < 2; ++ks) {
      bf16x8 af[4], bg[4];
#pragma unroll
      for (int i = 0; i < 4; ++i) {
        const int ra = wm * 64 + i * 16 + (lane & 15);
        const int ga = (ks * 4 + (lane >> 4)) ^ (ra & 7);
        af[i] = *(const bf16x8*)((const char*)smA + ra * 128 + ga * 16);
        const int rb = wn * 64 + i * 16 + (lane & 15);
        const int gb2 = (ks * 4 + (lane >> 4)) ^ (rb & 7);
        bg[i] = *(const bf16x8*)((const char*)smB + rb * 128 + gb2 * 16);
      }
#pragma unroll
      for (int i = 0; i < 4; ++i)
#pragma unroll
        for (int j = 0; j < 4; ++j)
          acc[i][j] = __builtin_amdgcn_mfma_f32_16x16x32_bf16(af[i], bg[j], acc[i][j], 0, 0, 0);
    }
  }

  const int r0 = wm * 64 + (lane >> 4) * 4;
  const int c0 = wn * 64 + (lane & 15);
#pragma unroll
  for (int j = 0; j < 4; ++j) {
    const long col = n0 + c0 + j * 16;
    float bv = 0.f;
    if (HASBIAS) bv = bias[col];
#pragma unroll
    for (int i = 0; i < 4; ++i) {
#pragma unroll
      for (int r = 0; r < 4; ++r) {
        const long row = m0 + r0 + i * 16 + r;
        C[row * N_ + col] = acc[i][j][r] + bv;
      }
    }
  }
}

// prep: rotary q,k; norms; normalize h>=10; fold sscale*log2e into q (geom0/2);
// emit fragment-linear tiles. Q2: [hi|lo] 8 frags/qw. K2: hi-only 8 frags/ktile.
// V2: 8 frags/ktile.
__global__ __launch_bounds__(256) void prep(
    const float* __restrict__ qkvf, unsigned short* __restrict__ Q2,
    unsigned short* __restrict__ K2, unsigned short* __restrict__ V2,
    float* __restrict__ qq, float* __restrict__ kk, const float* __restrict__ curvg) {
  __shared__ unsigned short Vl[64 * 66];
  const int tid = threadIdx.x;
  const int zz = blockIdx.x;
  const int ttile = zz & 31, bh = zz >> 5;
  const int b = bh >> 4, h = bh & 15;
  const int t0 = ttile * 64;
  const int tr = tid >> 2, seg = tid & 3;
  const int t = t0 + tr;
  const float* src = qkvf + ((size_t)(b * 2048 + t)) * 3072 + h * 64 + seg * 16;

  float qv[16], kv[16], vv[16];
#pragma unroll
  for (int c = 0; c < 4; ++c) {
    const f32x4 a  = *(const f32x4*)(src + c * 4);
    const f32x4 bb = *(const f32x4*)(src + 1024 + c * 4);
    const f32x4 cc = *(const f32x4*)(src + 2048 + c * 4);
#pragma unroll
    for (int e = 0; e < 4; ++e) { qv[c*4+e] = a[e]; kv[c*4+e] = bb[e]; vv[c*4+e] = cc[e]; }
  }
  float qr[16], kr[16];
#pragma unroll
  for (int e = 0; e < 16; ++e) {
    const int d = seg * 16 + e;
    const int i = d & 31;
    const float invf = exp2f(-0.41524101186109286f * (float)i);  // 10000^(-i/32)
    float sn, cs;
    sincosf((float)t * invf, &sn, &cs);
    const float qo = __shfl_xor(qv[e], 2, 64);
    const float ko = __shfl_xor(kv[e], 2, 64);
    qr[e] = (d < 32) ? (qv[e] * cs + qo * sn) : (qv[e] * cs - qo * sn);
    kr[e] = (d < 32) ? (kv[e] * cs + ko * sn) : (kv[e] * cs - ko * sn);
  }
  float sq = 0.f, sk = 0.f;
#pragma unroll
  for (int e = 0; e < 16; ++e) { sq += qr[e] * qr[e]; sk += kr[e] * kr[e]; }
  sq += __shfl_xor(sq, 1, 64); sq += __shfl_xor(sq, 2, 64);
  sk += __shfl_xor(sk, 1, 64); sk += __shfl_xor(sk, 2, 64);
  float qscale = 0.125f * 1.4426950408889634f;   // geom0: fold sscale*log2e
  if (h >= 10) {
    const float rq = 1.0f / fmaxf(sqrtf(sq), 1e-12f);
    const float rk = 1.0f / fmaxf(sqrtf(sk), 1e-12f);
#pragma unroll
    for (int e = 0; e < 16; ++e) { qr[e] *= rq; kr[e] *= rk; }
    qscale = 8.0f * 1.4426950408889634f;         // geom2
  } else if (h >= 6) {
    qscale = 1.0f;                                // geom1: raw dot needed
  }
#pragma unroll
  for (int e = 0; e < 16; ++e) qr[e] *= qscale;
  if (seg == 0) {
    const int idx = b * 32768 + h * 2048 + t;
    float oq = sq, ok = sk;
    if (h >= 6 && h < 10) {
      const float invc = 1.0f / curvg[h - 6];
      oq = sqrtf(invc + sq);
      ok = sqrtf(invc + sk);
    }
    qq[idx] = oq;
    kk[idx] = ok;
  }
  const int st = seg >> 1;
  const int quadA = (seg * 2) & 3, quadB = (seg * 2 + 1) & 3;
  {
    unsigned int wh[8], wl[8];
#pragma unroll
    for (int p = 0; p < 8; ++p) {
      unsigned short h0 = f2bf(qr[2*p]), h1 = f2bf(qr[2*p+1]);
      unsigned short l0 = f2bf(qr[2*p] - bf2f(h0)), l1 = f2bf(qr[2*p+1] - bf2f(h1));
      wh[p] = (unsigned)h0 | ((unsigned)h1 << 16);
      wl[p] = (unsigned)l0 | ((unsigned)l1 << 16);
    }
    const int qi = (t >> 4) & 1, c15q = t & 15;
    unsigned short* qs = Q2 + ((size_t)bh * 64 + (t >> 5)) * 4096;
    const int fh = ((qi * 2 + st) * 2 + 0) * 512, fl = fh + 512;
    *(uint4*)(qs + fh + quadA * 128 + c15q * 8) = uint4{wh[0], wh[1], wh[2], wh[3]};
    *(uint4*)(qs + fh + quadB * 128 + c15q * 8) = uint4{wh[4], wh[5], wh[6], wh[7]};
    *(uint4*)(qs + fl + quadA * 128 + c15q * 8) = uint4{wl[0], wl[1], wl[2], wl[3]};
    *(uint4*)(qs + fl + quadB * 128 + c15q * 8) = uint4{wl[4], wl[5], wl[6], wl[7]};
    // K: hi frags only
#pragma unroll
    for (int p = 0; p < 8; ++p) {
      unsigned short h0 = f2bf(kr[2*p]), h1 = f2bf(kr[2*p+1]);
      wh[p] = (unsigned)h0 | ((unsigned)h1 << 16);
    }
    const int kj = (tr >> 4) & 3, c15k = tr & 15;
    unsigned short* ks = K2 + ((size_t)bh * 32 + ttile) * 4096;
    const int gh = (st * 4 + kj) * 512;
    *(uint4*)(ks + gh + quadA * 128 + c15k * 8) = uint4{wh[0], wh[1], wh[2], wh[3]};
    *(uint4*)(ks + gh + quadB * 128 + c15k * 8) = uint4{wh[4], wh[5], wh[6], wh[7]};
  }
#pragma unroll
  for (int e = 0; e < 16; ++e) Vl[(seg * 16 + e) * 66 + tr] = f2bf(vv[e]);
  __syncthreads();
  {
    const int d = tid >> 2, tch = (tid & 3) * 16;
    unsigned int wv2[8];
#pragma unroll
    for (int p = 0; p < 8; ++p) {
      const unsigned short a0 = Vl[d * 66 + tch + 2*p];
      const unsigned short a1 = Vl[d * 66 + tch + 2*p + 1];
      wv2[p] = (unsigned)a0 | ((unsigned)a1 << 16);
    }
    const int dj = d >> 4, c15v = d & 15;
    const int ks2 = tch >> 5;
    const int qvA = (tch >> 3) & 3, qvB = ((tch >> 3) + 1) & 3;
    unsigned short* vs = V2 + ((size_t)bh * 32 + ttile) * 4096 + (ks2 * 4 + dj) * 512;
    *(uint4*)(vs + qvA * 128 + c15v * 8) = uint4{wv2[0], wv2[1], wv2[2], wv2[3]};
    *(uint4*)(vs + qvB * 128 + c15v * 8) = uint4{wv2[4], wv2[5], wv2[6], wv2[7]};
  }
}

// Split-K barrier-free MFMA flash attention. 2-product scores; geom0/2 scale folded
// into q -> p = exp2(s), no Moff. bh-major block order. 4 independent waves/WG.
// R18: K double-buffered; STAGE_K(next) issued AFTER the QK block (kf_cur dead
// there -> minimal buffer-lifetime overlap); V+tk staged at iter top (land
// under QK). __launch_bounds__(256,1): VGPR cap 512, allocator takes ~190.
__global__ __launch_bounds__(256, 1) void attn_part(
    const unsigned short* __restrict__ Q2, const unsigned short* __restrict__ K2,
    const unsigned short* __restrict__ V2, const float* __restrict__ tqq,
    const float* __restrict__ tkk, const float* __restrict__ curvg,
    float* __restrict__ part) {
  alignas(16) __shared__ unsigned short Pl[4][32 * 64];  // 4x 4KB wave-private P tiles
  const int tid = threadIdx.x;
  const int lane = tid & 63;
  const int wv = tid >> 6;
  unsigned short* Pw = &Pl[wv][0];
  const int quad = lane >> 4, c15 = lane & 15;
  const int z = blockIdx.x * 4 + wv;
  const int bh = z / 160;                // bh-major
  const int u = 159 - (z - bh * 160);    // big (qw,ch) first within the head
  int qw, ch;
  if (u < 16)      { qw = u; ch = 0; }
  else if (u < 48) { qw = 16 + ((u - 16) >> 1); ch = (u - 16) & 1; }
  else if (u < 96) { const int s2 = u - 48; const int q3 = s2 / 3; qw = 32 + q3; ch = s2 - 3 * q3; }
  else             { const int s2 = u - 96; qw = 48 + (s2 >> 2); ch = s2 & 3; }
  const int h = bh & 15;
  const int geom = (h < 6) ? 0 : ((h < 10) ? 1 : 2);
  const int qrow0 = qw * 32;
  const f32x4 zero4 = {0.f, 0.f, 0.f, 0.f};

  const unsigned short* qbase = Q2 + ((size_t)bh * 64 + qw) * 4096;
  bf16x8 qh[2][2], ql[2][2];
#pragma unroll
  for (int qi = 0; qi < 2; ++qi)
#pragma unroll
    for (int st = 0; st < 2; ++st) {
      const int f = ((qi * 2 + st) * 2) * 512 + lane * 8;
      qh[qi][st] = *(const bf16x8*)(qbase + f);
      ql[qi][st] = *(const bf16x8*)(qbase + f + 512);
    }

  float curv = 1.f, sic = 1.f;
  const float Moff = 4.0f;               // geom1 only
  f32x4 tq4[2] = {zero4, zero4};
  if (geom == 1) {
    curv = curvg[h - 6];
    sic = sqrtf(1.0f / curv);
#pragma unroll
    for (int qi = 0; qi < 2; ++qi)
      tq4[qi] = *(const f32x4*)(tqq + bh * 2048 + qrow0 + qi * 16 + quad * 4);
  }

  const __bf16 one_b = (__bf16)1.0f;
  const bf16x8 ones = {one_b, one_b, one_b, one_b, one_b, one_b, one_b, one_b};

  f32x4 o[2][4];
  f32x4 ol[2] = {zero4, zero4};
#pragma unroll
  for (int qi = 0; qi < 2; ++qi)
#pragma unroll
    for (int dj = 0; dj < 4; ++dj) o[qi][dj] = zero4;

  const int nkt = (qw >> 1) + 1;
  const int ktB = ch * 8;
  const int ktE = (ktB + 8 < nkt) ? (ktB + 8) : nkt;

  bf16x8 kfA[2][4], kfB[2][4];   // double-buffered K fragments
  bf16x8 vf[2][4];               // single-buffered V (lands under QK)
  float tkf[4];
  f32x4 s[2][4];

#define STAGE_V_TK(KT) do {                                                   \
    const unsigned short* vb_ = V2 + ((size_t)bh * 32 + (KT)) * 4096;         \
    _Pragma("unroll")                                                         \
    for (int ks2 = 0; ks2 < 2; ++ks2)                                         \
      _Pragma("unroll")                                                       \
      for (int dj = 0; dj < 4; ++dj)                                          \
        vf[ks2][dj] = *(const bf16x8*)(vb_ + (ks2 * 4 + dj) * 512 + lane * 8);\
    if (geom == 1) {                                                          \
      _Pragma("unroll")                                                       \
      for (int kj = 0; kj < 4; ++kj)                                          \
        tkf[kj] = tkk[bh * 2048 + (KT) * 64 + kj * 16 + c15];                 \
    }                                                                         \
  } while (0)

#define STAGE_K(KF, KT) do {                                                  \
    const unsigned short* kb_ = K2 + ((size_t)bh * 32 + (KT)) * 4096;         \
    _Pragma("unroll")                                                         \
    for (int st = 0; st < 2; ++st)                                            \
      _Pragma("unroll")                                                       \
      for (int kj = 0; kj < 4; ++kj)                                          \
        KF[st][kj] = *(const bf16x8*)(kb_ + (st * 4 + kj) * 512 + lane * 8);  \
  } while (0)

#define QK_COMPUTE(KF) do {                                                   \
    _Pragma("unroll")                                                         \
    for (int qi = 0; qi < 2; ++qi)                                            \
      _Pragma("unroll")                                                       \
      for (int kj = 0; kj < 4; ++kj) s[qi][kj] = zero4;                       \
    __builtin_amdgcn_s_setprio(1);                                            \
    _Pragma("unroll")                                                         \
    for (int st = 0; st < 2; ++st) {                                          \
      _Pragma("unroll")                                                       \
      for (int kj = 0; kj < 4; ++kj) {                                        \
        _Pragma("unroll")                                                     \
        for (int qi = 0; qi < 2; ++qi) {                                      \
          s[qi][kj] = __builtin_amdgcn_mfma_f32_16x16x32_bf16(qh[qi][st], KF[st][kj], s[qi][kj], 0, 0, 0); \
          s[qi][kj] = __builtin_amdgcn_mfma_f32_16x16x32_bf16(ql[qi][st], KF[st][kj], s[qi][kj], 0, 0, 0); \
        }                                                                     \
      }                                                                       \
    }                                                                         \
    __builtin_amdgcn_s_setprio(0);                                            \
  } while (0)

#define SM_PV(KT) do {                                                        \
    const int kb = (KT) * 64;                                                 \
    const bool needmask = ((KT) == nkt - 1);                                  \
    _Pragma("unroll")                                                         \
    for (int qi = 0; qi < 2; ++qi) {                                          \
      const int qbaserow = qrow0 + qi * 16 + quad * 4;                        \
      _Pragma("unroll")                                                       \
      for (int kj = 0; kj < 4; ++kj) {                                        \
        const int skey = kj * 16 + c15;                                       \
        const int key = kb + skey;                                            \
        const f32x4 d4 = s[qi][kj];                                           \
        f32x4 p;                                                              \
        if (geom == 1) {                                                      \
          const float tk = tkf[kj];                                           \
          _Pragma("unroll")                                                   \
          for (int r = 0; r < 4; ++r) {                                       \
            const float a = fmaxf(curv * (tq4[qi][r] * tk - d4[r]), 1.0f + 1e-7f); \
            const float dis = sic * __logf(a + sqrtf(a * a - 1.0f));          \
            p[r] = __expf(__builtin_amdgcn_rcpf(1e-6f + dis) - Moff);         \
          }                                                                   \
        } else {                                                              \
          _Pragma("unroll")                                                   \
          for (int r = 0; r < 4; ++r) p[r] = exp2f(d4[r]);                    \
        }                                                                     \
        if (needmask) {                                                       \
          _Pragma("unroll")                                                   \
          for (int r = 0; r < 4; ++r)                                         \
            if (key > qbaserow + r) p[r] = 0.0f;                              \
        }                                                                     \
        _Pragma("unroll")                                                     \
        for (int r = 0; r < 4; ++r) {                                         \
          union { float f; unsigned u2; } pv; pv.f = p[r];                    \
          const int row = qi * 16 + quad * 4 + r;                             \
          const int g = (skey >> 3) ^ (row & 7);                              \
          Pw[row * 64 + g * 8 + (skey & 7)] = (unsigned short)(pv.u2 >> 16);  \
        }                                                                     \
      }                                                                       \
    }                                                                         \
    __builtin_amdgcn_s_setprio(1);                                            \
    _Pragma("unroll")                                                         \
    for (int ks2 = 0; ks2 < 2; ++ks2) {                                       \
      bf16x8 av[2];                                                           \
      _Pragma("unroll")                                                       \
      for (int qi = 0; qi < 2; ++qi) {                                        \
        const int m = qi * 16 + c15;                                          \
        const int g = (ks2 * 4 + quad) ^ (m & 7);                             \
        av[qi] = *(const bf16x8*)(Pw + m * 64 + g * 8);                       \
        ol[qi] = __builtin_amdgcn_mfma_f32_16x16x32_bf16(av[qi], ones, ol[qi], 0, 0, 0); \
      }                                                                       \
      _Pragma("unroll")                                                       \
      for (int dj = 0; dj < 4; ++dj) {                                        \
        _Pragma("unroll")                                                     \
        for (int qi = 0; qi < 2; ++qi)                                        \
          o[qi][dj] = __builtin_amdgcn_mfma_f32_16x16x32_bf16(av[qi], vf[ks2][dj], o[qi][dj], 0, 0, 0); \
      }                                                                       \
    }                                                                         \
    __builtin_amdgcn_s_setprio(0);                                            \
  } while (0)

  STAGE_K(kfA, ktB);
  for (int kt = ktB; kt < ktE; ++kt) {
    const int nx = (kt + 1 < ktE) ? kt + 1 : kt;   // clamped: last prefetch is dead
    if ((kt - ktB) & 1) {
      STAGE_V_TK(kt);          // V+tk in flight, land under QK
      QK_COMPUTE(kfB);         // kfB dies here
      STAGE_K(kfA, nx);        // next K in flight, lands under SM+PV
      SM_PV(kt);
    } else {
      STAGE_V_TK(kt);
      QK_COMPUTE(kfA);         // kfA dies here
      STAGE_K(kfB, nx);
      SM_PV(kt);
    }
  }

#undef STAGE_V_TK
#undef STAGE_K
#undef QK_COMPUTE
#undef SM_PV

  // ---- partial write: slot = bh*160 + u, stride 2112 f32
  float* slot = part + (size_t)(bh * 160 + u) * 2112;
#pragma unroll
  for (int qi = 0; qi < 2; ++qi)
#pragma unroll
    for (int dj = 0; dj < 4; ++dj)
      *(f32x4*)(slot + (qi * 4 + dj) * 256 + lane * 4) = o[qi][dj];
  if (c15 == 0) {
#pragma unroll
    for (int qi = 0; qi < 2; ++qi)
      *(f32x4*)(slot + 2048 + qi * 16 + quad * 4) = ol[qi];
  }
}

// Sum chunk partials, divide, LDS-transpose, write A'y [hi|lo] (2048-wide).
// 4 waves per WG, wave-private Ol slice.
__global__ __launch_bounds__(256) void attn_reduce(
    const float* __restrict__ part, unsigned short* __restrict__ Ay) {
  __shared__ float Ol[4][32 * 65];
  const int tid = threadIdx.x;
  const int lane = tid & 63;
  const int wv = tid >> 6;
  float* Olw = &Ol[wv][0];
  const int quad = lane >> 4, c15 = lane & 15;
  const int z = blockIdx.x * 4 + wv, bh = z & 31, qw = 63 - (z >> 5);
  const int b = bh >> 4, h = bh & 15;
  const int G = qw >> 4;
  const int base = qw + 8 * G * (G - 1) + (qw & 15) * G;
  const float* slot0 = part + (size_t)(bh * 160 + base) * 2112;

  const f32x4 zero4 = {0.f, 0.f, 0.f, 0.f};
  f32x4 o[8];
  f32x4 l4[2] = {zero4, zero4};
#pragma unroll
  for (int i = 0; i < 8; ++i) o[i] = zero4;
  for (int chv = 0; chv <= G; ++chv) {
    const float* sl = slot0 + chv * 2112;
#pragma unroll
    for (int i = 0; i < 8; ++i) o[i] += *(const f32x4*)(sl + i * 256 + lane * 4);
#pragma unroll
    for (int qi = 0; qi < 2; ++qi)
      l4[qi] += *(const f32x4*)(sl + 2048 + qi * 16 + quad * 4);
  }
#pragma unroll
  for (int qi = 0; qi < 2; ++qi) {
    f32x4 invl;
#pragma unroll
    for (int r = 0; r < 4; ++r) invl[r] = __builtin_amdgcn_rcpf(l4[qi][r]);
#pragma unroll
    for (int dj = 0; dj < 4; ++dj) {
      const f32x4 val = o[qi * 4 + dj] * invl;
#pragma unroll
      for (int r = 0; r < 4; ++r)
        Olw[(qi * 16 + quad * 4 + r) * 65 + dj * 16 + c15] = val[r];
    }
  }
  __syncthreads();
  const int row = lane >> 1, half = lane & 1;
  const float* rp = Olw + row * 65 + half * 32;
  unsigned int uh[16], ul2[16];
#pragma unroll
  for (int p = 0; p < 16; ++p) {
    const float v0 = rp[2 * p], v1 = rp[2 * p + 1];
    const unsigned short h0 = f2bf(v0), h1 = f2bf(v1);
    const unsigned short g0 = f2bf(v0 - bf2f(h0)), g1 = f2bf(v1 - bf2f(h1));
    uh[p] = (unsigned)h0 | ((unsigned)h1 << 16);
    ul2[p] = (unsigned)g0 | ((unsigned)g1 << 16);
  }
  unsigned short* yp = Ay + ((size_t)(b * 2048 + qw * 32 + row)) * 2048 + h * 64 + half * 32;
#pragma unroll
  for (int c = 0; c < 4; ++c) {
    *(uint4*)(yp + 8 * c)        = uint4{uh[4*c], uh[4*c+1], uh[4*c+2], uh[4*c+3]};
    *(uint4*)(yp + 1024 + 8 * c) = uint4{ul2[4*c], ul2[4*c+1], ul2[4*c+2], ul2[4*c+3]};
  }
}

extern "C" void kernel_launch(void* const* d_in, const int* in_sizes, int n_in,
                              void* d_out, int out_size, void* d_ws, size_t ws_size,
                              hipStream_t stream) {
  const float* x      = (const float*)d_in[0];
  const float* qkv_w  = (const float*)d_in[1];
  const float* proj_w = (const float*)d_in[2];
  const float* proj_b = (const float*)d_in[3];
  const float* curvature = (const float*)d_in[4];
  float* out = (float*)d_out;

  char* ws = (char*)d_ws;
  unsigned short* AX   = (unsigned short*)ws;                     // 4096x2048 bf16
  unsigned short* BW   = (unsigned short*)(ws + 16777216);        // 3072x2048 bf16
  float*          QKVF = (float*)(ws + 33554432);                 // 4096x3072 f32
  unsigned short* Q2   = (unsigned short*)ws;                     // 16MB
  unsigned short* K2   = (unsigned short*)(ws + 16777216);        // 8MB (hi-only)
  unsigned short* V2   = (unsigned short*)(ws + 25165824);        // 8MB
  float*          PART = (float*)(ws + 33554432);                 // 43,253,760 B
  unsigned short* BPW  = (unsigned short*)(ws + 76808192);        // 1024x2048 bf16
  unsigned short* AY   = (unsigned short*)ws;                     // 4096x2048 bf16
  float*          QQ   = (float*)(ws + 94371840);
  float*          KK   = (float*)(ws + 94633984);

  split2<0><<<4096, 256, 0, stream>>>(x, AX);
  split2<1><<<3072, 256, 0, stream>>>(qkv_w, BW);

  gemm_bt<0><<<dim3(24, 32), 256, 0, stream>>>(AX, BW, QKVF, nullptr, 3072, 2048);

  prep<<<1024, 256, 0, stream>>>(QKVF, Q2, K2, V2, QQ, KK, curvature);

  split2<1><<<1024, 256, 0, stream>>>(proj_w, BPW);   // after prep: QKVF region free

  attn_part<<<1280, 256, 0, stream>>>(Q2, K2, V2, QQ, KK, curvature, PART);

  attn_reduce<<<512, 256, 0, stream>>>(PART, AY);

  gemm_bt<1><<<dim3(8, 32), 256, 0, stream>>>(AY, BPW, out, proj_b, 1024, 2048);
}

// Round 6
// 290.331 us; speedup vs baseline: 1.1956x; 1.1250x over previous
//
#include <hip/hip_runtime.h>
#include <stdint.h>
#include <math.h>

// MultiGeometryAttention — f32 in/out. B=2 T=2048 C=1024 H=16 HD=64.
// heads 0-5 sdpa(0.125) | 6-9 hyperbolic(curvature) | 10-15 cos-normalized sdpa(8).
// R13 (360->316us): 2-PRODUCT everywhere. GEMMs: x*W ~= (x_hi+x_lo)*W_hi via
// A'=[hi|lo], B'=[hi|hi], K'=2K. Attention: 2-product scores, K2 hi-only (8MB).
// Softmax: sscale*log2e folded into q (geom0/2), no Moff. bh-major block order.
// R14 (FAILED 486us): (256,4) -> VGPR 64 + spills. R15 (313us): (256,2), occupancy
// pinned ~13% by unified VGPR+AGPR tier, not WG shape.
// R16 (287us): per-ktile K/V batch load into regs -> attn_part 117->88us, VGPR 124.
// R17 (FAILED 347us): K-dbuf staged before compute -> clamp@128 + spills.
// R18 (327us): K-dbuf staged after QK + (256,1): clean (no spill, VGPR 156) but
// occupancy 13.5->8.6% while per-wave time -6% only => exposed-K latency is NOT
// the remaining stall; dependent chains are. VGPR>128 is a net loss. REVERTED.
// R19: attn_part = R16 exactly (88us Pareto point). New: rotgen kernel builds
// rotary cos/sin table (2048x32 float2, 512KB @ WS 83,886,080 — the free gap
// after QKVF); prep's 16 sincosf+16 exp2f per thread (4.2M device-wide) replaced
// by 8 f32x4 table loads. Predict prep -15..25us, total ~265-275us.
// WS (proven peak 94,896,128 B):
//  phase1: AX[0,16777216) BW[16777216,29360128) | QKVF[33554432,83886080)
//         ROT[83886080,84410368)
//  post-prep: Q2[0,16777216) K2hi[16777216,25165824) V2[25165824,33554432)
//             PART[33554432,76808192) BPW[76808192,81002496)
//  post-attn: AY[0,16777216) | QQ[94371840) KK[94633984)

typedef __bf16 bf16x8 __attribute__((ext_vector_type(8)));
typedef float f32x4 __attribute__((ext_vector_type(4)));

static __device__ __forceinline__ float bf2f(unsigned short u) {
  union { unsigned int i; float f; } v; v.i = ((unsigned int)u) << 16; return v.f;
}
static __device__ __forceinline__ unsigned short f2bf(float f) {
  union { float f; unsigned int i; } v; v.f = f;
  unsigned int x = v.i;
  x += 0x7fffu + ((x >> 16) & 1u);   // RNE
  return (unsigned short)(x >> 16);
}

// direct global->LDS async copy, 16B/lane (gemm staging only).
static __device__ __forceinline__ void async_copy16(const void* gsrc, void* ldst) {
  auto* lp = reinterpret_cast<__attribute__((address_space(3))) unsigned int*>(
      reinterpret_cast<uintptr_t>(ldst));
  auto* gp = reinterpret_cast<const __attribute__((address_space(1))) unsigned int*>(
      reinterpret_cast<uintptr_t>(gsrc));
  __builtin_amdgcn_global_load_lds(gp, lp, 16, 0, 0);
}

// rotary table: rt[t*32+i] = {cos, sin}(t * 10000^(-i/32)), t<2048, i<32.
__global__ __launch_bounds__(256) void rotgen(float* __restrict__ rt) {
  const int idx = blockIdx.x * 256 + threadIdx.x;   // 65536
  const int t = idx >> 5, i = idx & 31;
  const float invf = exp2f(-0.41524101186109286f * (float)i);  // 10000^(-i/32)
  float sn, cs;
  sincosf((float)t * invf, &sn, &cs);
  rt[idx * 2]     = cs;
  rt[idx * 2 + 1] = sn;
}

// f32 [rows][1024] -> split bf16 [rows][2048]. PAT=0 (A): [hi|lo]; PAT=1 (B): [hi|hi].
template <int PAT>
__global__ __launch_bounds__(256) void split2(const float* __restrict__ in,
                                              unsigned short* __restrict__ out) {
  const int row = blockIdx.x;
  const int kq = threadIdx.x * 4;
  const f32x4 x = *(const f32x4*)(in + (size_t)row * 1024 + kq);
  unsigned short hi[4], lo[4];
#pragma unroll
  for (int i = 0; i < 4; ++i) {
    hi[i] = f2bf(x[i]);
    lo[i] = f2bf(x[i] - bf2f(hi[i]));   // exact residual in f32
  }
  uint2 uh, ul;
  uh.x = (unsigned)hi[0] | ((unsigned)hi[1] << 16);
  uh.y = (unsigned)hi[2] | ((unsigned)hi[3] << 16);
  ul.x = (unsigned)lo[0] | ((unsigned)lo[1] << 16);
  ul.y = (unsigned)lo[2] | ((unsigned)lo[3] << 16);
  unsigned short* op = out + (size_t)row * 2048 + kq;
  *(uint2*)(op)        = uh;
  *(uint2*)(op + 1024) = PAT ? uh : ul;
}

// C[m][n] = sum_k A[m][k]*B[n][k] (+bias[n]) -> f32. 128x128 tile, BK=64, 4 waves,
// 16x16x32 bf16 MFMA, XOR-swizzled LDS (verified).
template <int HASBIAS>
__global__ __launch_bounds__(256) void gemm_bt(
    const unsigned short* __restrict__ A, const unsigned short* __restrict__ Bm,
    float* __restrict__ C, const float* __restrict__ bias, int N_, int K_) {
  alignas(16) __shared__ unsigned short smA[128 * 64];
  alignas(16) __shared__ unsigned short smB[128 * 64];
  const int tid = threadIdx.x;
  const int lane = tid & 63;
  const int wv = tid >> 6;
  const int wm = wv >> 1, wn = wv & 1;
  const long m0 = (long)blockIdx.y * 128, n0 = (long)blockIdx.x * 128;

  const f32x4 zero4 = {0.f, 0.f, 0.f, 0.f};
  f32x4 acc[4][4];
#pragma unroll
  for (int i = 0; i < 4; ++i)
#pragma unroll
    for (int j = 0; j < 4; ++j) acc[i][j] = zero4;

  int mrow[4], gg[4];
#pragma unroll
  for (int w = 0; w < 4; ++w) {
    int c = w * 256 + tid;
    mrow[w] = c >> 3;
    gg[w] = (c & 7) ^ ((c >> 3) & 7);
  }

  const int kTiles = K_ >> 6;
  for (int kt = 0; kt < kTiles; ++kt) {
    if (kt) __syncthreads();
    const int kb = kt << 6;
#pragma unroll
    for (int w = 0; w < 4; ++w) {
      const int c = w * 256 + tid;
      async_copy16(A + (size_t)(m0 + mrow[w]) * K_ + kb + gg[w] * 8,
                   (char*)smA + c * 16);
      async_copy16(Bm + (size_t)(n0 + mrow[w]) * K_ + kb + gg[w] * 8,
                   (char*)smB + c * 16);
    }
    __syncthreads();
#pragma unroll
    for (int ks = 0; ks < 2; ++ks) {
      bf16x8 af[4], bg[4];
#pragma unroll
      for (int i = 0; i < 4; ++i) {
        const int ra = wm * 64 + i * 16 + (lane & 15);
        const int ga = (ks * 4 + (lane >> 4)) ^ (ra & 7);
        af[i] = *(const bf16x8*)((const char*)smA + ra * 128 + ga * 16);
        const int rb = wn * 64 + i * 16 + (lane & 15);
        const int gb2 = (ks * 4 + (lane >> 4)) ^ (rb & 7);
        bg[i] = *(const bf16x8*)((const char*)smB + rb * 128 + gb2 * 16);
      }
#pragma unroll
      for (int i = 0; i < 4; ++i)
#pragma unroll
        for (int j = 0; j < 4; ++j)
          acc[i][j] = __builtin_amdgcn_mfma_f32_16x16x32_bf16(af[i], bg[j], acc[i][j], 0, 0, 0);
    }
  }

  const int r0 = wm * 64 + (lane >> 4) * 4;
  const int c0 = wn * 64 + (lane & 15);
#pragma unroll
  for (int j = 0; j < 4; ++j) {
    const long col = n0 + c0 + j * 16;
    float bv = 0.f;
    if (HASBIAS) bv = bias[col];
#pragma unroll
    for (int i = 0; i < 4; ++i) {
#pragma unroll
      for (int r = 0; r < 4; ++r) {
        const long row = m0 + r0 + i * 16 + r;
        C[row * N_ + col] = acc[i][j][r] + bv;
      }
    }
  }
}

// prep: rotary q,k (cos/sin from precomputed table); norms; normalize h>=10;
// fold sscale*log2e into q (geom0/2); emit fragment-linear tiles.
// Q2: [hi|lo] 8 frags/qw. K2: hi-only 8 frags/ktile. V2: 8 frags/ktile.
__global__ __launch_bounds__(256) void prep(
    const float* __restrict__ qkvf, unsigned short* __restrict__ Q2,
    unsigned short* __restrict__ K2, unsigned short* __restrict__ V2,
    float* __restrict__ qq, float* __restrict__ kk, const float* __restrict__ curvg,
    const float* __restrict__ rot) {
  __shared__ unsigned short Vl[64 * 66];
  const int tid = threadIdx.x;
  const int zz = blockIdx.x;
  const int ttile = zz & 31, bh = zz >> 5;
  const int b = bh >> 4, h = bh & 15;
  const int t0 = ttile * 64;
  const int tr = tid >> 2, seg = tid & 3;
  const int t = t0 + tr;
  const float* src = qkvf + ((size_t)(b * 2048 + t)) * 3072 + h * 64 + seg * 16;

  float qv[16], kv[16], vv[16];
#pragma unroll
  for (int c = 0; c < 4; ++c) {
    const f32x4 a  = *(const f32x4*)(src + c * 4);
    const f32x4 bb = *(const f32x4*)(src + 1024 + c * 4);
    const f32x4 cc = *(const f32x4*)(src + 2048 + c * 4);
#pragma unroll
    for (int e = 0; e < 4; ++e) { qv[c*4+e] = a[e]; kv[c*4+e] = bb[e]; vv[c*4+e] = cc[e]; }
  }
  // rotary table: i = (seg*16+e)&31 = (seg&1)*16 + e; 16 contiguous float2 = 8 f32x4
  float csv[16], snv[16];
  {
    const f32x4* rv = (const f32x4*)(rot + ((size_t)t * 32 + (seg & 1) * 16) * 2);
#pragma unroll
    for (int c = 0; c < 8; ++c) {
      const f32x4 w = rv[c];
      csv[2 * c]     = w[0];
      snv[2 * c]     = w[1];
      csv[2 * c + 1] = w[2];
      snv[2 * c + 1] = w[3];
    }
  }
  float qr[16], kr[16];
#pragma unroll
  for (int e = 0; e < 16; ++e) {
    const int d = seg * 16 + e;
    const float sn = snv[e], cs = csv[e];
    const float qo = __shfl_xor(qv[e], 2, 64);
    const float ko = __shfl_xor(kv[e], 2, 64);
    qr[e] = (d < 32) ? (qv[e] * cs + qo * sn) : (qv[e] * cs - qo * sn);
    kr[e] = (d < 32) ? (kv[e] * cs + ko * sn) : (kv[e] * cs - ko * sn);
  }
  float sq = 0.f, sk = 0.f;
#pragma unroll
  for (int e = 0; e < 16; ++e) { sq += qr[e] * qr[e]; sk += kr[e] * kr[e]; }
  sq += __shfl_xor(sq, 1, 64); sq += __shfl_xor(sq, 2, 64);
  sk += __shfl_xor(sk, 1, 64); sk += __shfl_xor(sk, 2, 64);
  float qscale = 0.125f * 1.4426950408889634f;   // geom0: fold sscale*log2e
  if (h >= 10) {
    const float rq = 1.0f / fmaxf(sqrtf(sq), 1e-12f);
    const float rk = 1.0f / fmaxf(sqrtf(sk), 1e-12f);
#pragma unroll
    for (int e = 0; e < 16; ++e) { qr[e] *= rq; kr[e] *= rk; }
    qscale = 8.0f * 1.4426950408889634f;         // geom2
  } else if (h >= 6) {
    qscale = 1.0f;                                // geom1: raw dot needed
  }
#pragma unroll
  for (int e = 0; e < 16; ++e) qr[e] *= qscale;
  if (seg == 0) {
    const int idx = b * 32768 + h * 2048 + t;
    float oq = sq, ok = sk;
    if (h >= 6 && h < 10) {
      const float invc = 1.0f / curvg[h - 6];
      oq = sqrtf(invc + sq);
      ok = sqrtf(invc + sk);
    }
    qq[idx] = oq;
    kk[idx] = ok;
  }
  const int st = seg >> 1;
  const int quadA = (seg * 2) & 3, quadB = (seg * 2 + 1) & 3;
  {
    unsigned int wh[8], wl[8];
#pragma unroll
    for (int p = 0; p < 8; ++p) {
      unsigned short h0 = f2bf(qr[2*p]), h1 = f2bf(qr[2*p+1]);
      unsigned short l0 = f2bf(qr[2*p] - bf2f(h0)), l1 = f2bf(qr[2*p+1] - bf2f(h1));
      wh[p] = (unsigned)h0 | ((unsigned)h1 << 16);
      wl[p] = (unsigned)l0 | ((unsigned)l1 << 16);
    }
    const int qi = (t >> 4) & 1, c15q = t & 15;
    unsigned short* qs = Q2 + ((size_t)bh * 64 + (t >> 5)) * 4096;
    const int fh = ((qi * 2 + st) * 2 + 0) * 512, fl = fh + 512;
    *(uint4*)(qs + fh + quadA * 128 + c15q * 8) = uint4{wh[0], wh[1], wh[2], wh[3]};
    *(uint4*)(qs + fh + quadB * 128 + c15q * 8) = uint4{wh[4], wh[5], wh[6], wh[7]};
    *(uint4*)(qs + fl + quadA * 128 + c15q * 8) = uint4{wl[0], wl[1], wl[2], wl[3]};
    *(uint4*)(qs + fl + quadB * 128 + c15q * 8) = uint4{wl[4], wl[5], wl[6], wl[7]};
    // K: hi frags only
#pragma unroll
    for (int p = 0; p < 8; ++p) {
      unsigned short h0 = f2bf(kr[2*p]), h1 = f2bf(kr[2*p+1]);
      wh[p] = (unsigned)h0 | ((unsigned)h1 << 16);
    }
    const int kj = (tr >> 4) & 3, c15k = tr & 15;
    unsigned short* ks = K2 + ((size_t)bh * 32 + ttile) * 4096;
    const int gh = (st * 4 + kj) * 512;
    *(uint4*)(ks + gh + quadA * 128 + c15k * 8) = uint4{wh[0], wh[1], wh[2], wh[3]};
    *(uint4*)(ks + gh + quadB * 128 + c15k * 8) = uint4{wh[4], wh[5], wh[6], wh[7]};
  }
#pragma unroll
  for (int e = 0; e < 16; ++e) Vl[(seg * 16 + e) * 66 + tr] = f2bf(vv[e]);
  __syncthreads();
  {
    const int d = tid >> 2, tch = (tid & 3) * 16;
    unsigned int wv2[8];
#pragma unroll
    for (int p = 0; p < 8; ++p) {
      const unsigned short a0 = Vl[d * 66 + tch + 2*p];
      const unsigned short a1 = Vl[d * 66 + tch + 2*p + 1];
      wv2[p] = (unsigned)a0 | ((unsigned)a1 << 16);
    }
    const int dj = d >> 4, c15v = d & 15;
    const int ks2 = tch >> 5;
    const int qvA = (tch >> 3) & 3, qvB = ((tch >> 3) + 1) & 3;
    unsigned short* vs = V2 + ((size_t)bh * 32 + ttile) * 4096 + (ks2 * 4 + dj) * 512;
    *(uint4*)(vs + qvA * 128 + c15v * 8) = uint4{wv2[0], wv2[1], wv2[2], wv2[3]};
    *(uint4*)(vs + qvB * 128 + c15v * 8) = uint4{wv2[4], wv2[5], wv2[6], wv2[7]};
  }
}

// Split-K barrier-free MFMA flash attention (R16 form — Pareto point).
// 2-product scores; geom0/2 scale folded into q -> p = exp2(s), no Moff.
// bh-major block order. 4 independent waves/WG. Per-ktile batch load of all
// 16 K/V frags (+geom1 tk) into registers: 16 loads in flight, ~1 exposed
// latency/ktile. VGPR 124 (<=128 tier). Do NOT raise VGPR past 128 (R17/R18:
// occupancy tier loss > pipeline gain).
__global__ __launch_bounds__(256, 2) void attn_part(
    const unsigned short* __restrict__ Q2, const unsigned short* __restrict__ K2,
    const unsigned short* __restrict__ V2, const float* __restrict__ tqq,
    const float* __restrict__ tkk, const float* __restrict__ curvg,
    float* __restrict__ part) {
  alignas(16) __shared__ unsigned short Pl[4][32 * 64];  // 4x 4KB wave-private P tiles
  const int tid = threadIdx.x;
  const int lane = tid & 63;
  const int wv = tid >> 6;
  unsigned short* Pw = &Pl[wv][0];
  const int quad = lane >> 4, c15 = lane & 15;
  const int z = blockIdx.x * 4 + wv;
  const int bh = z / 160;                // bh-major
  const int u = 159 - (z - bh * 160);    // big (qw,ch) first within the head
  int qw, ch;
  if (u < 16)      { qw = u; ch = 0; }
  else if (u < 48) { qw = 16 + ((u - 16) >> 1); ch = (u - 16) & 1; }
  else if (u < 96) { const int s2 = u - 48; const int q3 = s2 / 3; qw = 32 + q3; ch = s2 - 3 * q3; }
  else             { const int s2 = u - 96; qw = 48 + (s2 >> 2); ch = s2 & 3; }
  const int h = bh & 15;
  const int geom = (h < 6) ? 0 : ((h < 10) ? 1 : 2);
  const int qrow0 = qw * 32;
  const f32x4 zero4 = {0.f, 0.f, 0.f, 0.f};

  const unsigned short* qbase = Q2 + ((size_t)bh * 64 + qw) * 4096;
  bf16x8 qh[2][2], ql[2][2];
#pragma unroll
  for (int qi = 0; qi < 2; ++qi)
#pragma unroll
    for (int st = 0; st < 2; ++st) {
      const int f = ((qi * 2 + st) * 2) * 512 + lane * 8;
      qh[qi][st] = *(const bf16x8*)(qbase + f);
      ql[qi][st] = *(const bf16x8*)(qbase + f + 512);
    }

  float curv = 1.f, sic = 1.f;
  const float Moff = 4.0f;               // geom1 only
  f32x4 tq4[2] = {zero4, zero4};
  if (geom == 1) {
    curv = curvg[h - 6];
    sic = sqrtf(1.0f / curv);
#pragma unroll
    for (int qi = 0; qi < 2; ++qi)
      tq4[qi] = *(const f32x4*)(tqq + bh * 2048 + qrow0 + qi * 16 + quad * 4);
  }

  const __bf16 one_b = (__bf16)1.0f;
  const bf16x8 ones = {one_b, one_b, one_b, one_b, one_b, one_b, one_b, one_b};

  f32x4 o[2][4];
  f32x4 ol[2] = {zero4, zero4};
#pragma unroll
  for (int qi = 0; qi < 2; ++qi)
#pragma unroll
    for (int dj = 0; dj < 4; ++dj) o[qi][dj] = zero4;

  const int nkt = (qw >> 1) + 1;
  const int ktB = ch * 8;
  const int ktE = (ktB + 8 < nkt) ? (ktB + 8) : nkt;
  for (int kt = ktB; kt < ktE; ++kt) {
    const int kb = kt * 64;
    const unsigned short* kbase = K2 + ((size_t)bh * 32 + kt) * 4096;  // hi-only
    const unsigned short* vbase = V2 + ((size_t)bh * 32 + kt) * 4096;

    // ---- hoisted load batch: all 8 K-frags, then 8 V-frags, then geom1 tk.
    // Issue order = consumption order; first MFMA waits only for kf[0][0].
    bf16x8 kf[2][4], vf[2][4];
#pragma unroll
    for (int st = 0; st < 2; ++st)
#pragma unroll
      for (int kj = 0; kj < 4; ++kj)
        kf[st][kj] = *(const bf16x8*)(kbase + (st * 4 + kj) * 512 + lane * 8);
#pragma unroll
    for (int ks2 = 0; ks2 < 2; ++ks2)
#pragma unroll
      for (int dj = 0; dj < 4; ++dj)
        vf[ks2][dj] = *(const bf16x8*)(vbase + (ks2 * 4 + dj) * 512 + lane * 8);
    float tkf[4];
    if (geom == 1) {
#pragma unroll
      for (int kj = 0; kj < 4; ++kj)
        tkf[kj] = tkk[bh * 2048 + kb + kj * 16 + c15];
    }

    // ---- S = Q·K^T, 2-product (qh+ql)·kh
    f32x4 s[2][4];
#pragma unroll
    for (int qi = 0; qi < 2; ++qi)
#pragma unroll
      for (int kj = 0; kj < 4; ++kj) s[qi][kj] = zero4;
    __builtin_amdgcn_s_setprio(1);
#pragma unroll
    for (int st = 0; st < 2; ++st) {
#pragma unroll
      for (int kj = 0; kj < 4; ++kj) {
#pragma unroll
        for (int qi = 0; qi < 2; ++qi) {
          s[qi][kj] = __builtin_amdgcn_mfma_f32_16x16x32_bf16(qh[qi][st], kf[st][kj], s[qi][kj], 0, 0, 0);
          s[qi][kj] = __builtin_amdgcn_mfma_f32_16x16x32_bf16(ql[qi][st], kf[st][kj], s[qi][kj], 0, 0, 0);
        }
      }
    }
    __builtin_amdgcn_s_setprio(0);

    // ---- p: geom0/2 -> exp2(s) (scale pre-folded, no Moff); geom1 -> full transform
    const bool needmask = (kt == nkt - 1);
#pragma unroll
    for (int qi = 0; qi < 2; ++qi) {
      const int qbaserow = qrow0 + qi * 16 + quad * 4;
#pragma unroll
      for (int kj = 0; kj < 4; ++kj) {
        const int skey = kj * 16 + c15;
        const int key = kb + skey;
        const f32x4 d4 = s[qi][kj];
        f32x4 p;
        if (geom == 1) {
          const float tk = tkf[kj];
#pragma unroll
          for (int r = 0; r < 4; ++r) {
            const float a = fmaxf(curv * (tq4[qi][r] * tk - d4[r]), 1.0f + 1e-7f);
            const float dis = sic * __logf(a + sqrtf(a * a - 1.0f));
            p[r] = __expf(__builtin_amdgcn_rcpf(1e-6f + dis) - Moff);
          }
        } else {
#pragma unroll
          for (int r = 0; r < 4; ++r) p[r] = exp2f(d4[r]);
        }
        if (needmask) {
#pragma unroll
          for (int r = 0; r < 4; ++r)
            if (key > qbaserow + r) p[r] = 0.0f;
        }
#pragma unroll
        for (int r = 0; r < 4; ++r) {
          union { float f; unsigned u2; } pv; pv.f = p[r];
          const int row = qi * 16 + quad * 4 + r;
          const int g = (skey >> 3) ^ (row & 7);
          Pw[row * 64 + g * 8 + (skey & 7)] = (unsigned short)(pv.u2 >> 16);
        }
      }
    }

    // ---- PV: O += P·V^T ; l += P·1  (vf already resident)
    __builtin_amdgcn_s_setprio(1);
#pragma unroll
    for (int ks2 = 0; ks2 < 2; ++ks2) {
      bf16x8 av[2];
#pragma unroll
      for (int qi = 0; qi < 2; ++qi) {
        const int m = qi * 16 + c15;
        const int g = (ks2 * 4 + quad) ^ (m & 7);
        av[qi] = *(const bf16x8*)(Pw + m * 64 + g * 8);
        ol[qi] = __builtin_amdgcn_mfma_f32_16x16x32_bf16(av[qi], ones, ol[qi], 0, 0, 0);
      }
#pragma unroll
      for (int dj = 0; dj < 4; ++dj) {
#pragma unroll
        for (int qi = 0; qi < 2; ++qi)
          o[qi][dj] = __builtin_amdgcn_mfma_f32_16x16x32_bf16(av[qi], vf[ks2][dj], o[qi][dj], 0, 0, 0);
      }
    }
    __builtin_amdgcn_s_setprio(0);
  }

  // ---- partial write: slot = bh*160 + u, stride 2112 f32
  float* slot = part + (size_t)(bh * 160 + u) * 2112;
#pragma unroll
  for (int qi = 0; qi < 2; ++qi)
#pragma unroll
    for (int dj = 0; dj < 4; ++dj)
      *(f32x4*)(slot + (qi * 4 + dj) * 256 + lane * 4) = o[qi][dj];
  if (c15 == 0) {
#pragma unroll
    for (int qi = 0; qi < 2; ++qi)
      *(f32x4*)(slot + 2048 + qi * 16 + quad * 4) = ol[qi];
  }
}

// Sum chunk partials, divide, LDS-transpose, write A'y [hi|lo] (2048-wide).
// 4 waves per WG, wave-private Ol slice.
__global__ __launch_bounds__(256) void attn_reduce(
    const float* __restrict__ part, unsigned short* __restrict__ Ay) {
  __shared__ float Ol[4][32 * 65];
  const int tid = threadIdx.x;
  const int lane = tid & 63;
  const int wv = tid >> 6;
  float* Olw = &Ol[wv][0];
  const int quad = lane >> 4, c15 = lane & 15;
  const int z = blockIdx.x * 4 + wv, bh = z & 31, qw = 63 - (z >> 5);
  const int b = bh >> 4, h = bh & 15;
  const int G = qw >> 4;
  const int base = qw + 8 * G * (G - 1) + (qw & 15) * G;
  const float* slot0 = part + (size_t)(bh * 160 + base) * 2112;

  const f32x4 zero4 = {0.f, 0.f, 0.f, 0.f};
  f32x4 o[8];
  f32x4 l4[2] = {zero4, zero4};
#pragma unroll
  for (int i = 0; i < 8; ++i) o[i] = zero4;
  for (int chv = 0; chv <= G; ++chv) {
    const float* sl = slot0 + chv * 2112;
#pragma unroll
    for (int i = 0; i < 8; ++i) o[i] += *(const f32x4*)(sl + i * 256 + lane * 4);
#pragma unroll
    for (int qi = 0; qi < 2; ++qi)
      l4[qi] += *(const f32x4*)(sl + 2048 + qi * 16 + quad * 4);
  }
#pragma unroll
  for (int qi = 0; qi < 2; ++qi) {
    f32x4 invl;
#pragma unroll
    for (int r = 0; r < 4; ++r) invl[r] = __builtin_amdgcn_rcpf(l4[qi][r]);
#pragma unroll
    for (int dj = 0; dj < 4; ++dj) {
      const f32x4 val = o[qi * 4 + dj] * invl;
#pragma unroll
      for (int r = 0; r < 4; ++r)
        Olw[(qi * 16 + quad * 4 + r) * 65 + dj * 16 + c15] = val[r];
    }
  }
  __syncthreads();
  const int row = lane >> 1, half = lane & 1;
  const float* rp = Olw + row * 65 + half * 32;
  unsigned int uh[16], ul2[16];
#pragma unroll
  for (int p = 0; p < 16; ++p) {
    const float v0 = rp[2 * p], v1 = rp[2 * p + 1];
    const unsigned short h0 = f2bf(v0), h1 = f2bf(v1);
    const unsigned short g0 = f2bf(v0 - bf2f(h0)), g1 = f2bf(v1 - bf2f(h1));
    uh[p] = (unsigned)h0 | ((unsigned)h1 << 16);
    ul2[p] = (unsigned)g0 | ((unsigned)g1 << 16);
  }
  unsigned short* yp = Ay + ((size_t)(b * 2048 + qw * 32 + row)) * 2048 + h * 64 + half * 32;
#pragma unroll
  for (int c = 0; c < 4; ++c) {
    *(uint4*)(yp + 8 * c)        = uint4{uh[4*c], uh[4*c+1], uh[4*c+2], uh[4*c+3]};
    *(uint4*)(yp + 1024 + 8 * c) = uint4{ul2[4*c], ul2[4*c+1], ul2[4*c+2], ul2[4*c+3]};
  }
}

extern "C" void kernel_launch(void* const* d_in, const int* in_sizes, int n_in,
                              void* d_out, int out_size, void* d_ws, size_t ws_size,
                              hipStream_t stream) {
  const float* x      = (const float*)d_in[0];
  const float* qkv_w  = (const float*)d_in[1];
  const float* proj_w = (const float*)d_in[2];
  const float* proj_b = (const float*)d_in[3];
  const float* curvature = (const float*)d_in[4];
  float* out = (float*)d_out;

  char* ws = (char*)d_ws;
  unsigned short* AX   = (unsigned short*)ws;                     // 4096x2048 bf16
  unsigned short* BW   = (unsigned short*)(ws + 16777216);        // 3072x2048 bf16
  float*          QKVF = (float*)(ws + 33554432);                 // 4096x3072 f32
  float*          ROT  = (float*)(ws + 83886080);                 // 2048x32 float2 = 512KB
  unsigned short* Q2   = (unsigned short*)ws;                     // 16MB
  unsigned short* K2   = (unsigned short*)(ws + 16777216);        // 8MB (hi-only)
  unsigned short* V2   = (unsigned short*)(ws + 25165824);        // 8MB
  float*          PART = (float*)(ws + 33554432);                 // 43,253,760 B
  unsigned short* BPW  = (unsigned short*)(ws + 76808192);        // 1024x2048 bf16
  unsigned short* AY   = (unsigned short*)ws;                     // 4096x2048 bf16
  float*          QQ   = (float*)(ws + 94371840);
  float*          KK   = (float*)(ws + 94633984);

  rotgen<<<256, 256, 0, stream>>>(ROT);

  split2<0><<<4096, 256, 0, stream>>>(x, AX);
  split2<1><<<3072, 256, 0, stream>>>(qkv_w, BW);

  gemm_bt<0><<<dim3(24, 32), 256, 0, stream>>>(AX, BW, QKVF, nullptr, 3072, 2048);

  prep<<<1024, 256, 0, stream>>>(QKVF, Q2, K2, V2, QQ, KK, curvature, ROT);

  split2<1><<<1024, 256, 0, stream>>>(proj_w, BPW);   // after prep: QKVF region free

  attn_part<<<1280, 256, 0, stream>>>(Q2, K2, V2, QQ, KK, curvature, PART);

  attn_reduce<<<512, 256, 0, stream>>>(PART, AY);

  gemm_bt<1><<<dim3(8, 32), 256, 0, stream>>>(AY, BPW, out, proj_b, 1024, 2048);
}

// Round 7
// 285.200 us; speedup vs baseline: 1.2171x; 1.0180x over previous
//
#include <hip/hip_runtime.h>
#include <stdint.h>
#include <math.h>

// MultiGeometryAttention — f32 in/out. B=2 T=2048 C=1024 H=16 HD=64.
// heads 0-5 sdpa(0.125) | 6-9 hyperbolic(curvature) | 10-15 cos-normalized sdpa(8).
// R13 (360->316us): 2-PRODUCT everywhere. GEMMs: x*W ~= (x_hi+x_lo)*W_hi via
// A'=[hi|lo], B'=[hi|hi], K'=2K. Attention: 2-product scores, K2 hi-only (8MB).
// R14 (FAILED 486us): (256,4) -> VGPR 64 + spills. R15 (313us): (256,2).
// R16 (287us): per-ktile K/V batch load into regs -> attn_part 117->88us, VGPR 124.
// R17/R18 (FAILED/neutral): K double-buffer -> spills or occupancy-tier loss.
//   Lesson: VGPR>128 loses more occupancy than pipelining gains.
// R19 (290us): rotary table for prep = NEUTRAL -> prep not trig-bound; reverted.
// R20: attn_part counters (VALU 42% vs Mfma 12.9%) say the softmax->PV LDS
// round-trip (32 ds_write_b16 + swizzle addr VALU + lgkm serialize + 4 ds_read)
// is the cost. SWAPPED QK^T: sT=mfma(K,Q) (arg swap only; Q2/K2/V2 unchanged)
// -> lane holds P^T k-major; pack pairs (same >>16 truncation, bit-identical);
// PV B-frags assembled with 32 ds_bpermute + 16 cndmask; O^T=mfma(vf,pT);
// l=mfma(ones,pT). Pl LDS removed (16KB->0). PART slot layout internal:
// attn_reduce store index transposed + scalar-l divide. Predict attn 88->~75.
// WS (proven peak 94,896,128 B):
//  phase1: AX[0,16777216) BW[16777216,29360128) | QKVF[33554432,83886080)
//  post-prep: Q2[0,16777216) K2hi[16777216,25165824) V2[25165824,33554432)
//             PART[33554432,76808192) BPW[76808192,81002496)
//  post-attn: AY[0,16777216) | QQ[94371840) KK[94633984)

typedef __bf16 bf16x8 __attribute__((ext_vector_type(8)));
typedef float f32x4 __attribute__((ext_vector_type(4)));

static __device__ __forceinline__ float bf2f(unsigned short u) {
  union { unsigned int i; float f; } v; v.i = ((unsigned int)u) << 16; return v.f;
}
static __device__ __forceinline__ unsigned short f2bf(float f) {
  union { float f; unsigned int i; } v; v.f = f;
  unsigned int x = v.i;
  x += 0x7fffu + ((x >> 16) & 1u);   // RNE
  return (unsigned short)(x >> 16);
}

// direct global->LDS async copy, 16B/lane (gemm staging only).
static __device__ __forceinline__ void async_copy16(const void* gsrc, void* ldst) {
  auto* lp = reinterpret_cast<__attribute__((address_space(3))) unsigned int*>(
      reinterpret_cast<uintptr_t>(ldst));
  auto* gp = reinterpret_cast<const __attribute__((address_space(1))) unsigned int*>(
      reinterpret_cast<uintptr_t>(gsrc));
  __builtin_amdgcn_global_load_lds(gp, lp, 16, 0, 0);
}

// f32 [rows][1024] -> split bf16 [rows][2048]. PAT=0 (A): [hi|lo]; PAT=1 (B): [hi|hi].
template <int PAT>
__global__ __launch_bounds__(256) void split2(const float* __restrict__ in,
                                              unsigned short* __restrict__ out) {
  const int row = blockIdx.x;
  const int kq = threadIdx.x * 4;
  const f32x4 x = *(const f32x4*)(in + (size_t)row * 1024 + kq);
  unsigned short hi[4], lo[4];
#pragma unroll
  for (int i = 0; i < 4; ++i) {
    hi[i] = f2bf(x[i]);
    lo[i] = f2bf(x[i] - bf2f(hi[i]));   // exact residual in f32
  }
  uint2 uh, ul;
  uh.x = (unsigned)hi[0] | ((unsigned)hi[1] << 16);
  uh.y = (unsigned)hi[2] | ((unsigned)hi[3] << 16);
  ul.x = (unsigned)lo[0] | ((unsigned)lo[1] << 16);
  ul.y = (unsigned)lo[2] | ((unsigned)lo[3] << 16);
  unsigned short* op = out + (size_t)row * 2048 + kq;
  *(uint2*)(op)        = uh;
  *(uint2*)(op + 1024) = PAT ? uh : ul;
}

// C[m][n] = sum_k A[m][k]*B[n][k] (+bias[n]) -> f32. 128x128 tile, BK=64, 4 waves,
// 16x16x32 bf16 MFMA, XOR-swizzled LDS (verified).
template <int HASBIAS>
__global__ __launch_bounds__(256) void gemm_bt(
    const unsigned short* __restrict__ A, const unsigned short* __restrict__ Bm,
    float* __restrict__ C, const float* __restrict__ bias, int N_, int K_) {
  alignas(16) __shared__ unsigned short smA[128 * 64];
  alignas(16) __shared__ unsigned short smB[128 * 64];
  const int tid = threadIdx.x;
  const int lane = tid & 63;
  const int wv = tid >> 6;
  const int wm = wv >> 1, wn = wv & 1;
  const long m0 = (long)blockIdx.y * 128, n0 = (long)blockIdx.x * 128;

  const f32x4 zero4 = {0.f, 0.f, 0.f, 0.f};
  f32x4 acc[4][4];
#pragma unroll
  for (int i = 0; i < 4; ++i)
#pragma unroll
    for (int j = 0; j < 4; ++j) acc[i][j] = zero4;

  int mrow[4], gg[4];
#pragma unroll
  for (int w = 0; w < 4; ++w) {
    int c = w * 256 + tid;
    mrow[w] = c >> 3;
    gg[w] = (c & 7) ^ ((c >> 3) & 7);
  }

  const int kTiles = K_ >> 6;
  for (int kt = 0; kt < kTiles; ++kt) {
    if (kt) __syncthreads();
    const int kb = kt << 6;
#pragma unroll
    for (int w = 0; w < 4; ++w) {
      const int c = w * 256 + tid;
      async_copy16(A + (size_t)(m0 + mrow[w]) * K_ + kb + gg[w] * 8,
                   (char*)smA + c * 16);
      async_copy16(Bm + (size_t)(n0 + mrow[w]) * K_ + kb + gg[w] * 8,
                   (char*)smB + c * 16);
    }
    __syncthreads();
#pragma unroll
    for (int ks = 0; ks < 2; ++ks) {
      bf16x8 af[4], bg[4];
#pragma unroll
      for (int i = 0; i < 4; ++i) {
        const int ra = wm * 64 + i * 16 + (lane & 15);
        const int ga = (ks * 4 + (lane >> 4)) ^ (ra & 7);
        af[i] = *(const bf16x8*)((const char*)smA + ra * 128 + ga * 16);
        const int rb = wn * 64 + i * 16 + (lane & 15);
        const int gb2 = (ks * 4 + (lane >> 4)) ^ (rb & 7);
        bg[i] = *(const bf16x8*)((const char*)smB + rb * 128 + gb2 * 16);
      }
#pragma unroll
      for (int i = 0; i < 4; ++i)
#pragma unroll
        for (int j = 0; j < 4; ++j)
          acc[i][j] = __builtin_amdgcn_mfma_f32_16x16x32_bf16(af[i], bg[j], acc[i][j], 0, 0, 0);
    }
  }

  const int r0 = wm * 64 + (lane >> 4) * 4;
  const int c0 = wn * 64 + (lane & 15);
#pragma unroll
  for (int j = 0; j < 4; ++j) {
    const long col = n0 + c0 + j * 16;
    float bv = 0.f;
    if (HASBIAS) bv = bias[col];
#pragma unroll
    for (int i = 0; i < 4; ++i) {
#pragma unroll
      for (int r = 0; r < 4; ++r) {
        const long row = m0 + r0 + i * 16 + r;
        C[row * N_ + col] = acc[i][j][r] + bv;
      }
    }
  }
}

// prep: rotary q,k; norms; normalize h>=10; fold sscale*log2e into q (geom0/2);
// emit fragment-linear tiles. Q2: [hi|lo] 8 frags/qw. K2: hi-only 8 frags/ktile.
// V2: 8 frags/ktile.
__global__ __launch_bounds__(256) void prep(
    const float* __restrict__ qkvf, unsigned short* __restrict__ Q2,
    unsigned short* __restrict__ K2, unsigned short* __restrict__ V2,
    float* __restrict__ qq, float* __restrict__ kk, const float* __restrict__ curvg) {
  __shared__ unsigned short Vl[64 * 66];
  const int tid = threadIdx.x;
  const int zz = blockIdx.x;
  const int ttile = zz & 31, bh = zz >> 5;
  const int b = bh >> 4, h = bh & 15;
  const int t0 = ttile * 64;
  const int tr = tid >> 2, seg = tid & 3;
  const int t = t0 + tr;
  const float* src = qkvf + ((size_t)(b * 2048 + t)) * 3072 + h * 64 + seg * 16;

  float qv[16], kv[16], vv[16];
#pragma unroll
  for (int c = 0; c < 4; ++c) {
    const f32x4 a  = *(const f32x4*)(src + c * 4);
    const f32x4 bb = *(const f32x4*)(src + 1024 + c * 4);
    const f32x4 cc = *(const f32x4*)(src + 2048 + c * 4);
#pragma unroll
    for (int e = 0; e < 4; ++e) { qv[c*4+e] = a[e]; kv[c*4+e] = bb[e]; vv[c*4+e] = cc[e]; }
  }
  float qr[16], kr[16];
#pragma unroll
  for (int e = 0; e < 16; ++e) {
    const int d = seg * 16 + e;
    const int i = d & 31;
    const float invf = exp2f(-0.41524101186109286f * (float)i);  // 10000^(-i/32)
    float sn, cs;
    sincosf((float)t * invf, &sn, &cs);
    const float qo = __shfl_xor(qv[e], 2, 64);
    const float ko = __shfl_xor(kv[e], 2, 64);
    qr[e] = (d < 32) ? (qv[e] * cs + qo * sn) : (qv[e] * cs - qo * sn);
    kr[e] = (d < 32) ? (kv[e] * cs + ko * sn) : (kv[e] * cs - ko * sn);
  }
  float sq = 0.f, sk = 0.f;
#pragma unroll
  for (int e = 0; e < 16; ++e) { sq += qr[e] * qr[e]; sk += kr[e] * kr[e]; }
  sq += __shfl_xor(sq, 1, 64); sq += __shfl_xor(sq, 2, 64);
  sk += __shfl_xor(sk, 1, 64); sk += __shfl_xor(sk, 2, 64);
  float qscale = 0.125f * 1.4426950408889634f;   // geom0: fold sscale*log2e
  if (h >= 10) {
    const float rq = 1.0f / fmaxf(sqrtf(sq), 1e-12f);
    const float rk = 1.0f / fmaxf(sqrtf(sk), 1e-12f);
#pragma unroll
    for (int e = 0; e < 16; ++e) { qr[e] *= rq; kr[e] *= rk; }
    qscale = 8.0f * 1.4426950408889634f;         // geom2
  } else if (h >= 6) {
    qscale = 1.0f;                                // geom1: raw dot needed
  }
#pragma unroll
  for (int e = 0; e < 16; ++e) qr[e] *= qscale;
  if (seg == 0) {
    const int idx = b * 32768 + h * 2048 + t;
    float oq = sq, ok = sk;
    if (h >= 6 && h < 10) {
      const float invc = 1.0f / curvg[h - 6];
      oq = sqrtf(invc + sq);
      ok = sqrtf(invc + sk);
    }
    qq[idx] = oq;
    kk[idx] = ok;
  }
  const int st = seg >> 1;
  const int quadA = (seg * 2) & 3, quadB = (seg * 2 + 1) & 3;
  {
    unsigned int wh[8], wl[8];
#pragma unroll
    for (int p = 0; p < 8; ++p) {
      unsigned short h0 = f2bf(qr[2*p]), h1 = f2bf(qr[2*p+1]);
      unsigned short l0 = f2bf(qr[2*p] - bf2f(h0)), l1 = f2bf(qr[2*p+1] - bf2f(h1));
      wh[p] = (unsigned)h0 | ((unsigned)h1 << 16);
      wl[p] = (unsigned)l0 | ((unsigned)l1 << 16);
    }
    const int qi = (t >> 4) & 1, c15q = t & 15;
    unsigned short* qs = Q2 + ((size_t)bh * 64 + (t >> 5)) * 4096;
    const int fh = ((qi * 2 + st) * 2 + 0) * 512, fl = fh + 512;
    *(uint4*)(qs + fh + quadA * 128 + c15q * 8) = uint4{wh[0], wh[1], wh[2], wh[3]};
    *(uint4*)(qs + fh + quadB * 128 + c15q * 8) = uint4{wh[4], wh[5], wh[6], wh[7]};
    *(uint4*)(qs + fl + quadA * 128 + c15q * 8) = uint4{wl[0], wl[1], wl[2], wl[3]};
    *(uint4*)(qs + fl + quadB * 128 + c15q * 8) = uint4{wl[4], wl[5], wl[6], wl[7]};
    // K: hi frags only
#pragma unroll
    for (int p = 0; p < 8; ++p) {
      unsigned short h0 = f2bf(kr[2*p]), h1 = f2bf(kr[2*p+1]);
      wh[p] = (unsigned)h0 | ((unsigned)h1 << 16);
    }
    const int kj = (tr >> 4) & 3, c15k = tr & 15;
    unsigned short* ks = K2 + ((size_t)bh * 32 + ttile) * 4096;
    const int gh = (st * 4 + kj) * 512;
    *(uint4*)(ks + gh + quadA * 128 + c15k * 8) = uint4{wh[0], wh[1], wh[2], wh[3]};
    *(uint4*)(ks + gh + quadB * 128 + c15k * 8) = uint4{wh[4], wh[5], wh[6], wh[7]};
  }
#pragma unroll
  for (int e = 0; e < 16; ++e) Vl[(seg * 16 + e) * 66 + tr] = f2bf(vv[e]);
  __syncthreads();
  {
    const int d = tid >> 2, tch = (tid & 3) * 16;
    unsigned int wv2[8];
#pragma unroll
    for (int p = 0; p < 8; ++p) {
      const unsigned short a0 = Vl[d * 66 + tch + 2*p];
      const unsigned short a1 = Vl[d * 66 + tch + 2*p + 1];
      wv2[p] = (unsigned)a0 | ((unsigned)a1 << 16);
    }
    const int dj = d >> 4, c15v = d & 15;
    const int ks2 = tch >> 5;
    const int qvA = (tch >> 3) & 3, qvB = ((tch >> 3) + 1) & 3;
    unsigned short* vs = V2 + ((size_t)bh * 32 + ttile) * 4096 + (ks2 * 4 + dj) * 512;
    *(uint4*)(vs + qvA * 128 + c15v * 8) = uint4{wv2[0], wv2[1], wv2[2], wv2[3]};
    *(uint4*)(vs + qvB * 128 + c15v * 8) = uint4{wv2[4], wv2[5], wv2[6], wv2[7]};
  }
}

// Split-K barrier-free MFMA flash attention.
// R20: SWAPPED QK^T (sT = mfma(K,Q)) -> lane holds P^T k-major; softmax in
// registers; P packed to bf16 pairs (same truncation as before, bit-identical);
// PV B-frags via 32 ds_bpermute + 16 cndmask (no Pl LDS, no ds_write/ds_read).
// O^T = mfma(vf, pT); l = mfma(ones, pT). Per-ktile batch load of K/V kept
// (R16). VGPR must stay <=~128 tier (R17/R18 lesson).
__global__ __launch_bounds__(256, 2) void attn_part(
    const unsigned short* __restrict__ Q2, const unsigned short* __restrict__ K2,
    const unsigned short* __restrict__ V2, const float* __restrict__ tqq,
    const float* __restrict__ tkk, const float* __restrict__ curvg,
    float* __restrict__ part) {
  const int tid = threadIdx.x;
  const int lane = tid & 63;
  const int wv = tid >> 6;
  const int quad = lane >> 4, c15 = lane & 15;
  const int z = blockIdx.x * 4 + wv;
  const int bh = z / 160;                // bh-major
  const int u = 159 - (z - bh * 160);    // big (qw,ch) first within the head
  int qw, ch;
  if (u < 16)      { qw = u; ch = 0; }
  else if (u < 48) { qw = 16 + ((u - 16) >> 1); ch = (u - 16) & 1; }
  else if (u < 96) { const int s2 = u - 48; const int q3 = s2 / 3; qw = 32 + q3; ch = s2 - 3 * q3; }
  else             { const int s2 = u - 96; qw = 48 + (s2 >> 2); ch = s2 & 3; }
  const int h = bh & 15;
  const int geom = (h < 6) ? 0 : ((h < 10) ? 1 : 2);
  const int qrow0 = qw * 32;
  const f32x4 zero4 = {0.f, 0.f, 0.f, 0.f};

  const unsigned short* qbase = Q2 + ((size_t)bh * 64 + qw) * 4096;
  bf16x8 qh[2][2], ql[2][2];
#pragma unroll
  for (int qi = 0; qi < 2; ++qi)
#pragma unroll
    for (int st = 0; st < 2; ++st) {
      const int f = ((qi * 2 + st) * 2) * 512 + lane * 8;
      qh[qi][st] = *(const bf16x8*)(qbase + f);
      ql[qi][st] = *(const bf16x8*)(qbase + f + 512);
    }

  float curv = 1.f, sic = 1.f;
  const float Moff = 4.0f;               // geom1 only
  float tqs[2] = {0.f, 0.f};             // tq is now per-lane scalar (q = c15)
  if (geom == 1) {
    curv = curvg[h - 6];
    sic = sqrtf(1.0f / curv);
#pragma unroll
    for (int qi = 0; qi < 2; ++qi)
      tqs[qi] = tqq[bh * 2048 + qrow0 + qi * 16 + c15];
  }

  const __bf16 one_b = (__bf16)1.0f;
  const bf16x8 ones = {one_b, one_b, one_b, one_b, one_b, one_b, one_b, one_b};

  // bpermute byte indices: dest (quad,c15) pulls from src lanes
  // sA = ((quad&1)*2)*16 + c15 and sB = sA + 16 (byte idx = lane*4).
  const int iA = ((quad & 1) * 32 + c15) * 4;
  const int iB = iA + 64;
  const bool hiq = (quad >= 2);          // kj select: quads 0,1 -> a; 2,3 -> b

  f32x4 o[2][4];                         // O^T: elem r <-> d = dj*16+quad*4+r, col q = c15
  f32x4 ol[2] = {zero4, zero4};          // l[q=c15] replicated across r
#pragma unroll
  for (int qi = 0; qi < 2; ++qi)
#pragma unroll
    for (int dj = 0; dj < 4; ++dj) o[qi][dj] = zero4;

  const int nkt = (qw >> 1) + 1;
  const int ktB = ch * 8;
  const int ktE = (ktB + 8 < nkt) ? (ktB + 8) : nkt;
  for (int kt = ktB; kt < ktE; ++kt) {
    const int kb = kt * 64;
    const unsigned short* kbase = K2 + ((size_t)bh * 32 + kt) * 4096;  // hi-only
    const unsigned short* vbase = V2 + ((size_t)bh * 32 + kt) * 4096;

    // ---- hoisted load batch: 8 K-frags, 8 V-frags, geom1 tk (vector now).
    bf16x8 kf[2][4], vf[2][4];
#pragma unroll
    for (int st = 0; st < 2; ++st)
#pragma unroll
      for (int kj = 0; kj < 4; ++kj)
        kf[st][kj] = *(const bf16x8*)(kbase + (st * 4 + kj) * 512 + lane * 8);
#pragma unroll
    for (int ks2 = 0; ks2 < 2; ++ks2)
#pragma unroll
      for (int dj = 0; dj < 4; ++dj)
        vf[ks2][dj] = *(const bf16x8*)(vbase + (ks2 * 4 + dj) * 512 + lane * 8);
    f32x4 tk4[4];
    if (geom == 1) {
#pragma unroll
      for (int kj = 0; kj < 4; ++kj)
        tk4[kj] = *(const f32x4*)(tkk + bh * 2048 + kb + kj * 16 + quad * 4);
    }

    // ---- S^T = K·(Qh+Ql)^T : swapped args; lane holds S^T[k=kj*16+quad*4+r][q=c15]
    f32x4 s[2][4];
#pragma unroll
    for (int qi = 0; qi < 2; ++qi)
#pragma unroll
      for (int kj = 0; kj < 4; ++kj) s[qi][kj] = zero4;
    __builtin_amdgcn_s_setprio(1);
#pragma unroll
    for (int st = 0; st < 2; ++st) {
#pragma unroll
      for (int kj = 0; kj < 4; ++kj) {
#pragma unroll
        for (int qi = 0; qi < 2; ++qi) {
          s[qi][kj] = __builtin_amdgcn_mfma_f32_16x16x32_bf16(kf[st][kj], qh[qi][st], s[qi][kj], 0, 0, 0);
          s[qi][kj] = __builtin_amdgcn_mfma_f32_16x16x32_bf16(kf[st][kj], ql[qi][st], s[qi][kj], 0, 0, 0);
        }
      }
    }
    __builtin_amdgcn_s_setprio(0);

    // ---- softmax in registers -> packed bf16 pairs pw[qi][kj][2]
    const bool needmask = (kt == nkt - 1);
    unsigned pw[2][4][2];
#pragma unroll
    for (int qi = 0; qi < 2; ++qi) {
      const int qcol = qrow0 + qi * 16 + c15;
#pragma unroll
      for (int kj = 0; kj < 4; ++kj) {
        const int kloc = kb + kj * 16 + quad * 4;   // + r
        const f32x4 d4 = s[qi][kj];
        f32x4 p;
        if (geom == 1) {
          const float tq = tqs[qi];
#pragma unroll
          for (int r = 0; r < 4; ++r) {
            const float a = fmaxf(curv * (tq * tk4[kj][r] - d4[r]), 1.0f + 1e-7f);
            const float dis = sic * __logf(a + sqrtf(a * a - 1.0f));
            p[r] = __expf(__builtin_amdgcn_rcpf(1e-6f + dis) - Moff);
          }
        } else {
#pragma unroll
          for (int r = 0; r < 4; ++r) p[r] = exp2f(d4[r]);
        }
        if (needmask) {
#pragma unroll
          for (int r = 0; r < 4; ++r)
            if (kloc + r > qcol) p[r] = 0.0f;
        }
        union { float f; unsigned u2; } b0, b1, b2, b3;
        b0.f = p[0]; b1.f = p[1]; b2.f = p[2]; b3.f = p[3];
        pw[qi][kj][0] = (b0.u2 >> 16) | (b1.u2 & 0xffff0000u);   // (r0,r1) truncated
        pw[qi][kj][1] = (b2.u2 >> 16) | (b3.u2 & 0xffff0000u);   // (r2,r3)
      }
    }

    // ---- PV: O^T += V^T·P^T ; l += 1·P^T. B-frag per (qi,ks2): 8 bperm + 4 sel.
    __builtin_amdgcn_s_setprio(1);
#pragma unroll
    for (int ks2 = 0; ks2 < 2; ++ks2) {
      const int a = ks2 * 2, b2 = ks2 * 2 + 1;
#pragma unroll
      for (int qi = 0; qi < 2; ++qi) {
        const int w0A = __builtin_amdgcn_ds_bpermute(iA, (int)pw[qi][a][0]);
        const int w0B = __builtin_amdgcn_ds_bpermute(iA, (int)pw[qi][b2][0]);
        const int w1A = __builtin_amdgcn_ds_bpermute(iA, (int)pw[qi][a][1]);
        const int w1B = __builtin_amdgcn_ds_bpermute(iA, (int)pw[qi][b2][1]);
        const int w2A = __builtin_amdgcn_ds_bpermute(iB, (int)pw[qi][a][0]);
        const int w2B = __builtin_amdgcn_ds_bpermute(iB, (int)pw[qi][b2][0]);
        const int w3A = __builtin_amdgcn_ds_bpermute(iB, (int)pw[qi][a][1]);
        const int w3B = __builtin_amdgcn_ds_bpermute(iB, (int)pw[qi][b2][1]);
        union { uint4 u; bf16x8 v; } pf;
        pf.u.x = (unsigned)(hiq ? w0B : w0A);
        pf.u.y = (unsigned)(hiq ? w1B : w1A);
        pf.u.z = (unsigned)(hiq ? w2B : w2A);
        pf.u.w = (unsigned)(hiq ? w3B : w3A);
        const bf16x8 pfrag = pf.v;
        ol[qi] = __builtin_amdgcn_mfma_f32_16x16x32_bf16(ones, pfrag, ol[qi], 0, 0, 0);
#pragma unroll
        for (int dj = 0; dj < 4; ++dj)
          o[qi][dj] = __builtin_amdgcn_mfma_f32_16x16x32_bf16(vf[ks2][dj], pfrag, o[qi][dj], 0, 0, 0);
      }
    }
    __builtin_amdgcn_s_setprio(0);
  }

  // ---- partial write: slot = bh*160 + u, stride 2112 f32 (O^T layout, internal)
  float* slot = part + (size_t)(bh * 160 + u) * 2112;
#pragma unroll
  for (int qi = 0; qi < 2; ++qi)
#pragma unroll
    for (int dj = 0; dj < 4; ++dj)
      *(f32x4*)(slot + (qi * 4 + dj) * 256 + lane * 4) = o[qi][dj];
  if (quad == 0) {
#pragma unroll
    for (int qi = 0; qi < 2; ++qi)
      slot[2048 + qi * 16 + c15] = ol[qi][0];
  }
}

// Sum chunk partials, divide, LDS-transpose, write A'y [hi|lo] (2048-wide).
// 4 waves per WG, wave-private Ol slice. R20: slots hold O^T (elem r <->
// d=dj*16+quad*4+r, q=qi*16+c15); l is scalar per lane (q=c15).
__global__ __launch_bounds__(256) void attn_reduce(
    const float* __restrict__ part, unsigned short* __restrict__ Ay) {
  __shared__ float Ol[4][32 * 65];
  const int tid = threadIdx.x;
  const int lane = tid & 63;
  const int wv = tid >> 6;
  float* Olw = &Ol[wv][0];
  const int quad = lane >> 4, c15 = lane & 15;
  const int z = blockIdx.x * 4 + wv, bh = z & 31, qw = 63 - (z >> 5);
  const int b = bh >> 4, h = bh & 15;
  const int G = qw >> 4;
  const int base = qw + 8 * G * (G - 1) + (qw & 15) * G;
  const float* slot0 = part + (size_t)(bh * 160 + base) * 2112;

  const f32x4 zero4 = {0.f, 0.f, 0.f, 0.f};
  f32x4 o[8];
  float ls[2] = {0.f, 0.f};
#pragma unroll
  for (int i = 0; i < 8; ++i) o[i] = zero4;
  for (int chv = 0; chv <= G; ++chv) {
    const float* sl = slot0 + chv * 2112;
#pragma unroll
    for (int i = 0; i < 8; ++i) o[i] += *(const f32x4*)(sl + i * 256 + lane * 4);
#pragma unroll
    for (int qi = 0; qi < 2; ++qi)
      ls[qi] += sl[2048 + qi * 16 + c15];
  }
#pragma unroll
  for (int qi = 0; qi < 2; ++qi) {
    const float invl = __builtin_amdgcn_rcpf(ls[qi]);
#pragma unroll
    for (int dj = 0; dj < 4; ++dj) {
      const f32x4 val = o[qi * 4 + dj] * invl;
#pragma unroll
      for (int r = 0; r < 4; ++r)
        Olw[(qi * 16 + c15) * 65 + dj * 16 + quad * 4 + r] = val[r];
    }
  }
  __syncthreads();
  const int row = lane >> 1, half = lane & 1;
  const float* rp = Olw + row * 65 + half * 32;
  unsigned int uh[16], ul2[16];
#pragma unroll
  for (int p = 0; p < 16; ++p) {
    const float v0 = rp[2 * p], v1 = rp[2 * p + 1];
    const unsigned short h0 = f2bf(v0), h1 = f2bf(v1);
    const unsigned short g0 = f2bf(v0 - bf2f(h0)), g1 = f2bf(v1 - bf2f(h1));
    uh[p] = (unsigned)h0 | ((unsigned)h1 << 16);
    ul2[p] = (unsigned)g0 | ((unsigned)g1 << 16);
  }
  unsigned short* yp = Ay + ((size_t)(b * 2048 + qw * 32 + row)) * 2048 + h * 64 + half * 32;
#pragma unroll
  for (int c = 0; c < 4; ++c) {
    *(uint4*)(yp + 8 * c)        = uint4{uh[4*c], uh[4*c+1], uh[4*c+2], uh[4*c+3]};
    *(uint4*)(yp + 1024 + 8 * c) = uint4{ul2[4*c], ul2[4*c+1], ul2[4*c+2], ul2[4*c+3]};
  }
}

extern "C" void kernel_launch(void* const* d_in, const int* in_sizes, int n_in,
                              void* d_out, int out_size, void* d_ws, size_t ws_size,
                              hipStream_t stream) {
  const float* x      = (const float*)d_in[0];
  const float* qkv_w  = (const float*)d_in[1];
  const float* proj_w = (const float*)d_in[2];
  const float* proj_b = (const float*)d_in[3];
  const float* curvature = (const float*)d_in[4];
  float* out = (float*)d_out;

  char* ws = (char*)d_ws;
  unsigned short* AX   = (unsigned short*)ws;                     // 4096x2048 bf16
  unsigned short* BW   = (unsigned short*)(ws + 16777216);        // 3072x2048 bf16
  float*          QKVF = (float*)(ws + 33554432);                 // 4096x3072 f32
  unsigned short* Q2   = (unsigned short*)ws;                     // 16MB
  unsigned short* K2   = (unsigned short*)(ws + 16777216);        // 8MB (hi-only)
  unsigned short* V2   = (unsigned short*)(ws + 25165824);        // 8MB
  float*          PART = (float*)(ws + 33554432);                 // 43,253,760 B
  unsigned short* BPW  = (unsigned short*)(ws + 76808192);        // 1024x2048 bf16
  unsigned short* AY   = (unsigned short*)ws;                     // 4096x2048 bf16
  float*          QQ   = (float*)(ws + 94371840);
  float*          KK   = (float*)(ws + 94633984);

  split2<0><<<4096, 256, 0, stream>>>(x, AX);
  split2<1><<<3072, 256, 0, stream>>>(qkv_w, BW);

  gemm_bt<0><<<dim3(24, 32), 256, 0, stream>>>(AX, BW, QKVF, nullptr, 3072, 2048);

  prep<<<1024, 256, 0, stream>>>(QKVF, Q2, K2, V2, QQ, KK, curvature);

  split2<1><<<1024, 256, 0, stream>>>(proj_w, BPW);   // after prep: QKVF region free

  attn_part<<<1280, 256, 0, stream>>>(Q2, K2, V2, QQ, KK, curvature, PART);

  attn_reduce<<<512, 256, 0, stream>>>(PART, AY);

  gemm_bt<1><<<dim3(8, 32), 256, 0, stream>>>(AY, BPW, out, proj_b, 1024, 2048);
}

// Round 8
// 278.347 us; speedup vs baseline: 1.2470x; 1.0246x over previous
//
#include <hip/hip_runtime.h>
#include <stdint.h>
#include <math.h>

// MultiGeometryAttention — f32 in/out. B=2 T=2048 C=1024 H=16 HD=64.
// heads 0-5 sdpa(0.125) | 6-9 hyperbolic(curvature) | 10-15 cos-normalized sdpa(8).
// R13 (360->316us): 2-PRODUCT everywhere. R16 (287us): attn per-ktile K/V batch
// loads -> 88us. R17/R18: K-dbuf FAILED (VGPR>128 = occupancy-tier loss).
// R19: prep rotary table NEUTRAL (not trig-bound). R20 (285us): swapped QK^T +
// in-register P via ds_bpermute (LDS 16KB->0, VGPR 124->108) — NEUTRAL on time
// => attn floor is dependent-chain bound at ~1 wave/SIMD; attn_part parked at 87us.
// R21: GEMMs restructured like attn's K2-hi-only trick: A=[hi|lo] (2K wide),
// B stored HI-ONLY (K=1024 wide), two MFMAs per frag pair (hi*b, lo*b).
// Same MFMA count; LDS staging -25%, barrier pairs halved (16 vs 32 k-tiles),
// B fetch + split work halved. + bijective XCD swizzle (nwg%8==0) for A-panel
// L2 locality. Sync structure unchanged (stage->sync->compute) — no race risk.
// Predict gemm0 ~90->~67, total 285 -> ~258.
// WS (proven peak 94,896,128 B):
//  phase1: AX[0,16777216) BW1[16777216,23068672) | QKVF[33554432,83886080)
//  post-prep: Q2[0,16777216) K2hi[16777216,25165824) V2[25165824,33554432)
//             PART[33554432,76808192) BPW1[76808192,78905344)
//  post-attn: AY[0,16777216) | QQ[94371840) KK[94633984)

typedef __bf16 bf16x8 __attribute__((ext_vector_type(8)));
typedef float f32x4 __attribute__((ext_vector_type(4)));

static __device__ __forceinline__ float bf2f(unsigned short u) {
  union { unsigned int i; float f; } v; v.i = ((unsigned int)u) << 16; return v.f;
}
static __device__ __forceinline__ unsigned short f2bf(float f) {
  union { float f; unsigned int i; } v; v.f = f;
  unsigned int x = v.i;
  x += 0x7fffu + ((x >> 16) & 1u);   // RNE
  return (unsigned short)(x >> 16);
}

// direct global->LDS async copy, 16B/lane (gemm staging only).
static __device__ __forceinline__ void async_copy16(const void* gsrc, void* ldst) {
  auto* lp = reinterpret_cast<__attribute__((address_space(3))) unsigned int*>(
      reinterpret_cast<uintptr_t>(ldst));
  auto* gp = reinterpret_cast<const __attribute__((address_space(1))) unsigned int*>(
      reinterpret_cast<uintptr_t>(gsrc));
  __builtin_amdgcn_global_load_lds(gp, lp, 16, 0, 0);
}

// f32 [rows][1024] -> split bf16 [rows][2048] [hi|lo] (A-operand form).
template <int PAT>
__global__ __launch_bounds__(256) void split2(const float* __restrict__ in,
                                              unsigned short* __restrict__ out) {
  const int row = blockIdx.x;
  const int kq = threadIdx.x * 4;
  const f32x4 x = *(const f32x4*)(in + (size_t)row * 1024 + kq);
  unsigned short hi[4], lo[4];
#pragma unroll
  for (int i = 0; i < 4; ++i) {
    hi[i] = f2bf(x[i]);
    lo[i] = f2bf(x[i] - bf2f(hi[i]));   // exact residual in f32
  }
  uint2 uh, ul;
  uh.x = (unsigned)hi[0] | ((unsigned)hi[1] << 16);
  uh.y = (unsigned)hi[2] | ((unsigned)hi[3] << 16);
  ul.x = (unsigned)lo[0] | ((unsigned)lo[1] << 16);
  ul.y = (unsigned)lo[2] | ((unsigned)lo[3] << 16);
  unsigned short* op = out + (size_t)row * 2048 + kq;
  *(uint2*)(op)        = uh;
  *(uint2*)(op + 1024) = PAT ? uh : ul;
}

// f32 [rows][1024] -> bf16 hi-only [rows][1024] (B-operand form).
__global__ __launch_bounds__(256) void split1(const float* __restrict__ in,
                                              unsigned short* __restrict__ out) {
  const int row = blockIdx.x;
  const int kq = threadIdx.x * 4;
  const f32x4 x = *(const f32x4*)(in + (size_t)row * 1024 + kq);
  uint2 uh;
  uh.x = (unsigned)f2bf(x[0]) | ((unsigned)f2bf(x[1]) << 16);
  uh.y = (unsigned)f2bf(x[2]) | ((unsigned)f2bf(x[3]) << 16);
  *(uint2*)(out + (size_t)row * 1024 + kq) = uh;
}

// C[m][n] = sum_k (Ahi[m][k]+Alo[m][k])*B[n][k] (+bias[n]) -> f32.
// A: [M][2*Kr] hi|lo. B: [N][Kr] hi-only. 128x128 tile, BK=64 real-k, 4 waves,
// two MFMAs per frag pair. XOR-swizzled LDS (same verified scheme). 1D grid
// with bijective XCD swizzle (requires nwg%8==0).
template <int HASBIAS>
__global__ __launch_bounds__(256) void gemm_bt2(
    const unsigned short* __restrict__ A, const unsigned short* __restrict__ Bm,
    float* __restrict__ C, const float* __restrict__ bias,
    int NX, int N_, int Kr) {
  alignas(16) __shared__ unsigned short smAh[128 * 64];
  alignas(16) __shared__ unsigned short smAl[128 * 64];
  alignas(16) __shared__ unsigned short smB [128 * 64];
  const int tid = threadIdx.x;
  const int lane = tid & 63;
  const int wvi = tid >> 6;
  const int wm = wvi >> 1, wn = wvi & 1;
  // bijective XCD swizzle: XCD j (= bid%8) gets contiguous wgid chunk.
  const int cpx = gridDim.x >> 3;
  const int wgid = ((int)blockIdx.x & 7) * cpx + ((int)blockIdx.x >> 3);
  const long m0 = (long)(wgid / NX) * 128, n0 = (long)(wgid % NX) * 128;
  const int K2w = Kr * 2;

  const f32x4 zero4 = {0.f, 0.f, 0.f, 0.f};
  f32x4 acc[4][4];
#pragma unroll
  for (int i = 0; i < 4; ++i)
#pragma unroll
    for (int j = 0; j < 4; ++j) acc[i][j] = zero4;

  int mrow[4], gg[4];
#pragma unroll
  for (int w = 0; w < 4; ++w) {
    int c = w * 256 + tid;
    mrow[w] = c >> 3;
    gg[w] = (c & 7) ^ ((c >> 3) & 7);
  }

  const int kTiles = Kr >> 6;
  for (int kt = 0; kt < kTiles; ++kt) {
    if (kt) __syncthreads();
    const int kb = kt << 6;
#pragma unroll
    for (int w = 0; w < 4; ++w) {
      const int c = w * 256 + tid;
      const size_t arow = (size_t)(m0 + mrow[w]) * K2w + kb + gg[w] * 8;
      async_copy16(A + arow,        (char*)smAh + c * 16);
      async_copy16(A + arow + Kr,   (char*)smAl + c * 16);
      async_copy16(Bm + (size_t)(n0 + mrow[w]) * Kr + kb + gg[w] * 8,
                   (char*)smB + c * 16);
    }
    __syncthreads();
#pragma unroll
    for (int ks = 0; ks < 2; ++ks) {
      bf16x8 afh[4], afl[4], bg[4];
#pragma unroll
      for (int i = 0; i < 4; ++i) {
        const int ra = wm * 64 + i * 16 + (lane & 15);
        const int ga = (ks * 4 + (lane >> 4)) ^ (ra & 7);
        afh[i] = *(const bf16x8*)((const char*)smAh + ra * 128 + ga * 16);
        afl[i] = *(const bf16x8*)((const char*)smAl + ra * 128 + ga * 16);
        const int rb = wn * 64 + i * 16 + (lane & 15);
        const int gb2 = (ks * 4 + (lane >> 4)) ^ (rb & 7);
        bg[i] = *(const bf16x8*)((const char*)smB + rb * 128 + gb2 * 16);
      }
#pragma unroll
      for (int i = 0; i < 4; ++i)
#pragma unroll
        for (int j = 0; j < 4; ++j) {
          acc[i][j] = __builtin_amdgcn_mfma_f32_16x16x32_bf16(afh[i], bg[j], acc[i][j], 0, 0, 0);
          acc[i][j] = __builtin_amdgcn_mfma_f32_16x16x32_bf16(afl[i], bg[j], acc[i][j], 0, 0, 0);
        }
    }
  }

  const int r0 = wm * 64 + (lane >> 4) * 4;
  const int c0 = wn * 64 + (lane & 15);
#pragma unroll
  for (int j = 0; j < 4; ++j) {
    const long col = n0 + c0 + j * 16;
    float bv = 0.f;
    if (HASBIAS) bv = bias[col];
#pragma unroll
    for (int i = 0; i < 4; ++i) {
#pragma unroll
      for (int r = 0; r < 4; ++r) {
        const long row = m0 + r0 + i * 16 + r;
        C[row * N_ + col] = acc[i][j][r] + bv;
      }
    }
  }
}

// prep: rotary q,k; norms; normalize h>=10; fold sscale*log2e into q (geom0/2);
// emit fragment-linear tiles. Q2: [hi|lo] 8 frags/qw. K2: hi-only 8 frags/ktile.
// V2: 8 frags/ktile.
__global__ __launch_bounds__(256) void prep(
    const float* __restrict__ qkvf, unsigned short* __restrict__ Q2,
    unsigned short* __restrict__ K2, unsigned short* __restrict__ V2,
    float* __restrict__ qq, float* __restrict__ kk, const float* __restrict__ curvg) {
  __shared__ unsigned short Vl[64 * 66];
  const int tid = threadIdx.x;
  const int zz = blockIdx.x;
  const int ttile = zz & 31, bh = zz >> 5;
  const int b = bh >> 4, h = bh & 15;
  const int t0 = ttile * 64;
  const int tr = tid >> 2, seg = tid & 3;
  const int t = t0 + tr;
  const float* src = qkvf + ((size_t)(b * 2048 + t)) * 3072 + h * 64 + seg * 16;

  float qv[16], kv[16], vv[16];
#pragma unroll
  for (int c = 0; c < 4; ++c) {
    const f32x4 a  = *(const f32x4*)(src + c * 4);
    const f32x4 bb = *(const f32x4*)(src + 1024 + c * 4);
    const f32x4 cc = *(const f32x4*)(src + 2048 + c * 4);
#pragma unroll
    for (int e = 0; e < 4; ++e) { qv[c*4+e] = a[e]; kv[c*4+e] = bb[e]; vv[c*4+e] = cc[e]; }
  }
  float qr[16], kr[16];
#pragma unroll
  for (int e = 0; e < 16; ++e) {
    const int d = seg * 16 + e;
    const int i = d & 31;
    const float invf = exp2f(-0.41524101186109286f * (float)i);  // 10000^(-i/32)
    float sn, cs;
    sincosf((float)t * invf, &sn, &cs);
    const float qo = __shfl_xor(qv[e], 2, 64);
    const float ko = __shfl_xor(kv[e], 2, 64);
    qr[e] = (d < 32) ? (qv[e] * cs + qo * sn) : (qv[e] * cs - qo * sn);
    kr[e] = (d < 32) ? (kv[e] * cs + ko * sn) : (kv[e] * cs - ko * sn);
  }
  float sq = 0.f, sk = 0.f;
#pragma unroll
  for (int e = 0; e < 16; ++e) { sq += qr[e] * qr[e]; sk += kr[e] * kr[e]; }
  sq += __shfl_xor(sq, 1, 64); sq += __shfl_xor(sq, 2, 64);
  sk += __shfl_xor(sk, 1, 64); sk += __shfl_xor(sk, 2, 64);
  float qscale = 0.125f * 1.4426950408889634f;   // geom0: fold sscale*log2e
  if (h >= 10) {
    const float rq = 1.0f / fmaxf(sqrtf(sq), 1e-12f);
    const float rk = 1.0f / fmaxf(sqrtf(sk), 1e-12f);
#pragma unroll
    for (int e = 0; e < 16; ++e) { qr[e] *= rq; kr[e] *= rk; }
    qscale = 8.0f * 1.4426950408889634f;         // geom2
  } else if (h >= 6) {
    qscale = 1.0f;                                // geom1: raw dot needed
  }
#pragma unroll
  for (int e = 0; e < 16; ++e) qr[e] *= qscale;
  if (seg == 0) {
    const int idx = b * 32768 + h * 2048 + t;
    float oq = sq, ok = sk;
    if (h >= 6 && h < 10) {
      const float invc = 1.0f / curvg[h - 6];
      oq = sqrtf(invc + sq);
      ok = sqrtf(invc + sk);
    }
    qq[idx] = oq;
    kk[idx] = ok;
  }
  const int st = seg >> 1;
  const int quadA = (seg * 2) & 3, quadB = (seg * 2 + 1) & 3;
  {
    unsigned int wh[8], wl[8];
#pragma unroll
    for (int p = 0; p < 8; ++p) {
      unsigned short h0 = f2bf(qr[2*p]), h1 = f2bf(qr[2*p+1]);
      unsigned short l0 = f2bf(qr[2*p] - bf2f(h0)), l1 = f2bf(qr[2*p+1] - bf2f(h1));
      wh[p] = (unsigned)h0 | ((unsigned)h1 << 16);
      wl[p] = (unsigned)l0 | ((unsigned)l1 << 16);
    }
    const int qi = (t >> 4) & 1, c15q = t & 15;
    unsigned short* qs = Q2 + ((size_t)bh * 64 + (t >> 5)) * 4096;
    const int fh = ((qi * 2 + st) * 2 + 0) * 512, fl = fh + 512;
    *(uint4*)(qs + fh + quadA * 128 + c15q * 8) = uint4{wh[0], wh[1], wh[2], wh[3]};
    *(uint4*)(qs + fh + quadB * 128 + c15q * 8) = uint4{wh[4], wh[5], wh[6], wh[7]};
    *(uint4*)(qs + fl + quadA * 128 + c15q * 8) = uint4{wl[0], wl[1], wl[2], wl[3]};
    *(uint4*)(qs + fl + quadB * 128 + c15q * 8) = uint4{wl[4], wl[5], wl[6], wl[7]};
    // K: hi frags only
#pragma unroll
    for (int p = 0; p < 8; ++p) {
      unsigned short h0 = f2bf(kr[2*p]), h1 = f2bf(kr[2*p+1]);
      wh[p] = (unsigned)h0 | ((unsigned)h1 << 16);
    }
    const int kj = (tr >> 4) & 3, c15k = tr & 15;
    unsigned short* ks = K2 + ((size_t)bh * 32 + ttile) * 4096;
    const int gh = (st * 4 + kj) * 512;
    *(uint4*)(ks + gh + quadA * 128 + c15k * 8) = uint4{wh[0], wh[1], wh[2], wh[3]};
    *(uint4*)(ks + gh + quadB * 128 + c15k * 8) = uint4{wh[4], wh[5], wh[6], wh[7]};
  }
#pragma unroll
  for (int e = 0; e < 16; ++e) Vl[(seg * 16 + e) * 66 + tr] = f2bf(vv[e]);
  __syncthreads();
  {
    const int d = tid >> 2, tch = (tid & 3) * 16;
    unsigned int wv2[8];
#pragma unroll
    for (int p = 0; p < 8; ++p) {
      const unsigned short a0 = Vl[d * 66 + tch + 2*p];
      const unsigned short a1 = Vl[d * 66 + tch + 2*p + 1];
      wv2[p] = (unsigned)a0 | ((unsigned)a1 << 16);
    }
    const int dj = d >> 4, c15v = d & 15;
    const int ks2 = tch >> 5;
    const int qvA = (tch >> 3) & 3, qvB = ((tch >> 3) + 1) & 3;
    unsigned short* vs = V2 + ((size_t)bh * 32 + ttile) * 4096 + (ks2 * 4 + dj) * 512;
    *(uint4*)(vs + qvA * 128 + c15v * 8) = uint4{wv2[0], wv2[1], wv2[2], wv2[3]};
    *(uint4*)(vs + qvB * 128 + c15v * 8) = uint4{wv2[4], wv2[5], wv2[6], wv2[7]};
  }
}

// Split-K barrier-free MFMA flash attention (R20 form — parked at ~87us).
// Swapped QK^T (sT=mfma(K,Q)); softmax in registers; P via ds_bpermute;
// O^T=mfma(vf,pT); l=mfma(ones,pT). Per-ktile batch K/V loads (R16).
__global__ __launch_bounds__(256, 2) void attn_part(
    const unsigned short* __restrict__ Q2, const unsigned short* __restrict__ K2,
    const unsigned short* __restrict__ V2, const float* __restrict__ tqq,
    const float* __restrict__ tkk, const float* __restrict__ curvg,
    float* __restrict__ part) {
  const int tid = threadIdx.x;
  const int lane = tid & 63;
  const int wv = tid >> 6;
  const int quad = lane >> 4, c15 = lane & 15;
  const int z = blockIdx.x * 4 + wv;
  const int bh = z / 160;                // bh-major
  const int u = 159 - (z - bh * 160);    // big (qw,ch) first within the head
  int qw, ch;
  if (u < 16)      { qw = u; ch = 0; }
  else if (u < 48) { qw = 16 + ((u - 16) >> 1); ch = (u - 16) & 1; }
  else if (u < 96) { const int s2 = u - 48; const int q3 = s2 / 3; qw = 32 + q3; ch = s2 - 3 * q3; }
  else             { const int s2 = u - 96; qw = 48 + (s2 >> 2); ch = s2 & 3; }
  const int h = bh & 15;
  const int geom = (h < 6) ? 0 : ((h < 10) ? 1 : 2);
  const int qrow0 = qw * 32;
  const f32x4 zero4 = {0.f, 0.f, 0.f, 0.f};

  const unsigned short* qbase = Q2 + ((size_t)bh * 64 + qw) * 4096;
  bf16x8 qh[2][2], ql[2][2];
#pragma unroll
  for (int qi = 0; qi < 2; ++qi)
#pragma unroll
    for (int st = 0; st < 2; ++st) {
      const int f = ((qi * 2 + st) * 2) * 512 + lane * 8;
      qh[qi][st] = *(const bf16x8*)(qbase + f);
      ql[qi][st] = *(const bf16x8*)(qbase + f + 512);
    }

  float curv = 1.f, sic = 1.f;
  const float Moff = 4.0f;               // geom1 only
  float tqs[2] = {0.f, 0.f};             // tq per-lane scalar (q = c15)
  if (geom == 1) {
    curv = curvg[h - 6];
    sic = sqrtf(1.0f / curv);
#pragma unroll
    for (int qi = 0; qi < 2; ++qi)
      tqs[qi] = tqq[bh * 2048 + qrow0 + qi * 16 + c15];
  }

  const __bf16 one_b = (__bf16)1.0f;
  const bf16x8 ones = {one_b, one_b, one_b, one_b, one_b, one_b, one_b, one_b};

  const int iA = ((quad & 1) * 32 + c15) * 4;
  const int iB = iA + 64;
  const bool hiq = (quad >= 2);

  f32x4 o[2][4];
  f32x4 ol[2] = {zero4, zero4};
#pragma unroll
  for (int qi = 0; qi < 2; ++qi)
#pragma unroll
    for (int dj = 0; dj < 4; ++dj) o[qi][dj] = zero4;

  const int nkt = (qw >> 1) + 1;
  const int ktB = ch * 8;
  const int ktE = (ktB + 8 < nkt) ? (ktB + 8) : nkt;
  for (int kt = ktB; kt < ktE; ++kt) {
    const int kb = kt * 64;
    const unsigned short* kbase = K2 + ((size_t)bh * 32 + kt) * 4096;  // hi-only
    const unsigned short* vbase = V2 + ((size_t)bh * 32 + kt) * 4096;

    bf16x8 kf[2][4], vf[2][4];
#pragma unroll
    for (int st = 0; st < 2; ++st)
#pragma unroll
      for (int kj = 0; kj < 4; ++kj)
        kf[st][kj] = *(const bf16x8*)(kbase + (st * 4 + kj) * 512 + lane * 8);
#pragma unroll
    for (int ks2 = 0; ks2 < 2; ++ks2)
#pragma unroll
      for (int dj = 0; dj < 4; ++dj)
        vf[ks2][dj] = *(const bf16x8*)(vbase + (ks2 * 4 + dj) * 512 + lane * 8);
    f32x4 tk4[4];
    if (geom == 1) {
#pragma unroll
      for (int kj = 0; kj < 4; ++kj)
        tk4[kj] = *(const f32x4*)(tkk + bh * 2048 + kb + kj * 16 + quad * 4);
    }

    // ---- S^T = K·(Qh+Ql)^T
    f32x4 s[2][4];
#pragma unroll
    for (int qi = 0; qi < 2; ++qi)
#pragma unroll
      for (int kj = 0; kj < 4; ++kj) s[qi][kj] = zero4;
    __builtin_amdgcn_s_setprio(1);
#pragma unroll
    for (int st = 0; st < 2; ++st) {
#pragma unroll
      for (int kj = 0; kj < 4; ++kj) {
#pragma unroll
        for (int qi = 0; qi < 2; ++qi) {
          s[qi][kj] = __builtin_amdgcn_mfma_f32_16x16x32_bf16(kf[st][kj], qh[qi][st], s[qi][kj], 0, 0, 0);
          s[qi][kj] = __builtin_amdgcn_mfma_f32_16x16x32_bf16(kf[st][kj], ql[qi][st], s[qi][kj], 0, 0, 0);
        }
      }
    }
    __builtin_amdgcn_s_setprio(0);

    // ---- softmax in registers -> packed bf16 pairs
    const bool needmask = (kt == nkt - 1);
    unsigned pw[2][4][2];
#pragma unroll
    for (int qi = 0; qi < 2; ++qi) {
      const int qcol = qrow0 + qi * 16 + c15;
#pragma unroll
      for (int kj = 0; kj < 4; ++kj) {
        const int kloc = kb + kj * 16 + quad * 4;
        const f32x4 d4 = s[qi][kj];
        f32x4 p;
        if (geom == 1) {
          const float tq = tqs[qi];
#pragma unroll
          for (int r = 0; r < 4; ++r) {
            const float a = fmaxf(curv * (tq * tk4[kj][r] - d4[r]), 1.0f + 1e-7f);
            const float dis = sic * __logf(a + sqrtf(a * a - 1.0f));
            p[r] = __expf(__builtin_amdgcn_rcpf(1e-6f + dis) - Moff);
          }
        } else {
#pragma unroll
          for (int r = 0; r < 4; ++r) p[r] = exp2f(d4[r]);
        }
        if (needmask) {
#pragma unroll
          for (int r = 0; r < 4; ++r)
            if (kloc + r > qcol) p[r] = 0.0f;
        }
        union { float f; unsigned u2; } b0, b1, b2, b3;
        b0.f = p[0]; b1.f = p[1]; b2.f = p[2]; b3.f = p[3];
        pw[qi][kj][0] = (b0.u2 >> 16) | (b1.u2 & 0xffff0000u);
        pw[qi][kj][1] = (b2.u2 >> 16) | (b3.u2 & 0xffff0000u);
      }
    }

    // ---- PV via bpermute-assembled P fragments
    __builtin_amdgcn_s_setprio(1);
#pragma unroll
    for (int ks2 = 0; ks2 < 2; ++ks2) {
      const int a = ks2 * 2, b2 = ks2 * 2 + 1;
#pragma unroll
      for (int qi = 0; qi < 2; ++qi) {
        const int w0A = __builtin_amdgcn_ds_bpermute(iA, (int)pw[qi][a][0]);
        const int w0B = __builtin_amdgcn_ds_bpermute(iA, (int)pw[qi][b2][0]);
        const int w1A = __builtin_amdgcn_ds_bpermute(iA, (int)pw[qi][a][1]);
        const int w1B = __builtin_amdgcn_ds_bpermute(iA, (int)pw[qi][b2][1]);
        const int w2A = __builtin_amdgcn_ds_bpermute(iB, (int)pw[qi][a][0]);
        const int w2B = __builtin_amdgcn_ds_bpermute(iB, (int)pw[qi][b2][0]);
        const int w3A = __builtin_amdgcn_ds_bpermute(iB, (int)pw[qi][a][1]);
        const int w3B = __builtin_amdgcn_ds_bpermute(iB, (int)pw[qi][b2][1]);
        union { uint4 u; bf16x8 v; } pf;
        pf.u.x = (unsigned)(hiq ? w0B : w0A);
        pf.u.y = (unsigned)(hiq ? w1B : w1A);
        pf.u.z = (unsigned)(hiq ? w2B : w2A);
        pf.u.w = (unsigned)(hiq ? w3B : w3A);
        const bf16x8 pfrag = pf.v;
        ol[qi] = __builtin_amdgcn_mfma_f32_16x16x32_bf16(ones, pfrag, ol[qi], 0, 0, 0);
#pragma unroll
        for (int dj = 0; dj < 4; ++dj)
          o[qi][dj] = __builtin_amdgcn_mfma_f32_16x16x32_bf16(vf[ks2][dj], pfrag, o[qi][dj], 0, 0, 0);
      }
    }
    __builtin_amdgcn_s_setprio(0);
  }

  // ---- partial write: slot = bh*160 + u, stride 2112 f32 (O^T layout, internal)
  float* slot = part + (size_t)(bh * 160 + u) * 2112;
#pragma unroll
  for (int qi = 0; qi < 2; ++qi)
#pragma unroll
    for (int dj = 0; dj < 4; ++dj)
      *(f32x4*)(slot + (qi * 4 + dj) * 256 + lane * 4) = o[qi][dj];
  if (quad == 0) {
#pragma unroll
    for (int qi = 0; qi < 2; ++qi)
      slot[2048 + qi * 16 + c15] = ol[qi][0];
  }
}

// Sum chunk partials, divide, LDS-transpose, write A'y [hi|lo] (2048-wide).
// Slots hold O^T (elem r <-> d=dj*16+quad*4+r, q=qi*16+c15); l scalar per lane.
__global__ __launch_bounds__(256) void attn_reduce(
    const float* __restrict__ part, unsigned short* __restrict__ Ay) {
  __shared__ float Ol[4][32 * 65];
  const int tid = threadIdx.x;
  const int lane = tid & 63;
  const int wv = tid >> 6;
  float* Olw = &Ol[wv][0];
  const int quad = lane >> 4, c15 = lane & 15;
  const int z = blockIdx.x * 4 + wv, bh = z & 31, qw = 63 - (z >> 5);
  const int b = bh >> 4, h = bh & 15;
  const int G = qw >> 4;
  const int base = qw + 8 * G * (G - 1) + (qw & 15) * G;
  const float* slot0 = part + (size_t)(bh * 160 + base) * 2112;

  const f32x4 zero4 = {0.f, 0.f, 0.f, 0.f};
  f32x4 o[8];
  float ls[2] = {0.f, 0.f};
#pragma unroll
  for (int i = 0; i < 8; ++i) o[i] = zero4;
  for (int chv = 0; chv <= G; ++chv) {
    const float* sl = slot0 + chv * 2112;
#pragma unroll
    for (int i = 0; i < 8; ++i) o[i] += *(const f32x4*)(sl + i * 256 + lane * 4);
#pragma unroll
    for (int qi = 0; qi < 2; ++qi)
      ls[qi] += sl[2048 + qi * 16 + c15];
  }
#pragma unroll
  for (int qi = 0; qi < 2; ++qi) {
    const float invl = __builtin_amdgcn_rcpf(ls[qi]);
#pragma unroll
    for (int dj = 0; dj < 4; ++dj) {
      const f32x4 val = o[qi * 4 + dj] * invl;
#pragma unroll
      for (int r = 0; r < 4; ++r)
        Olw[(qi * 16 + c15) * 65 + dj * 16 + quad * 4 + r] = val[r];
    }
  }
  __syncthreads();
  const int row = lane >> 1, half = lane & 1;
  const float* rp = Olw + row * 65 + half * 32;
  unsigned int uh[16], ul2[16];
#pragma unroll
  for (int p = 0; p < 16; ++p) {
    const float v0 = rp[2 * p], v1 = rp[2 * p + 1];
    const unsigned short h0 = f2bf(v0), h1 = f2bf(v1);
    const unsigned short g0 = f2bf(v0 - bf2f(h0)), g1 = f2bf(v1 - bf2f(h1));
    uh[p] = (unsigned)h0 | ((unsigned)h1 << 16);
    ul2[p] = (unsigned)g0 | ((unsigned)g1 << 16);
  }
  unsigned short* yp = Ay + ((size_t)(b * 2048 + qw * 32 + row)) * 2048 + h * 64 + half * 32;
#pragma unroll
  for (int c = 0; c < 4; ++c) {
    *(uint4*)(yp + 8 * c)        = uint4{uh[4*c], uh[4*c+1], uh[4*c+2], uh[4*c+3]};
    *(uint4*)(yp + 1024 + 8 * c) = uint4{ul2[4*c], ul2[4*c+1], ul2[4*c+2], ul2[4*c+3]};
  }
}

extern "C" void kernel_launch(void* const* d_in, const int* in_sizes, int n_in,
                              void* d_out, int out_size, void* d_ws, size_t ws_size,
                              hipStream_t stream) {
  const float* x      = (const float*)d_in[0];
  const float* qkv_w  = (const float*)d_in[1];
  const float* proj_w = (const float*)d_in[2];
  const float* proj_b = (const float*)d_in[3];
  const float* curvature = (const float*)d_in[4];
  float* out = (float*)d_out;

  char* ws = (char*)d_ws;
  unsigned short* AX   = (unsigned short*)ws;                     // 4096x2048 bf16 hi|lo
  unsigned short* BW1  = (unsigned short*)(ws + 16777216);        // 3072x1024 bf16 hi
  float*          QKVF = (float*)(ws + 33554432);                 // 4096x3072 f32
  unsigned short* Q2   = (unsigned short*)ws;                     // 16MB
  unsigned short* K2   = (unsigned short*)(ws + 16777216);        // 8MB (hi-only)
  unsigned short* V2   = (unsigned short*)(ws + 25165824);        // 8MB
  float*          PART = (float*)(ws + 33554432);                 // 43,253,760 B
  unsigned short* BPW1 = (unsigned short*)(ws + 76808192);        // 1024x1024 bf16 hi
  unsigned short* AY   = (unsigned short*)ws;                     // 4096x2048 bf16 hi|lo
  float*          QQ   = (float*)(ws + 94371840);
  float*          KK   = (float*)(ws + 94633984);

  split2<0><<<4096, 256, 0, stream>>>(x, AX);
  split1<<<3072, 256, 0, stream>>>(qkv_w, BW1);

  // M=4096 N=3072 Kr=1024: 32x24 = 768 wgs (768%8==0 for XCD swizzle)
  gemm_bt2<0><<<768, 256, 0, stream>>>(AX, BW1, QKVF, nullptr, 24, 3072, 1024);

  prep<<<1024, 256, 0, stream>>>(QKVF, Q2, K2, V2, QQ, KK, curvature);

  split1<<<1024, 256, 0, stream>>>(proj_w, BPW1);   // after prep: QKVF region free

  attn_part<<<1280, 256, 0, stream>>>(Q2, K2, V2, QQ, KK, curvature, PART);

  attn_reduce<<<512, 256, 0, stream>>>(PART, AY);

  // M=4096 N=1024 Kr=1024: 32x8 = 256 wgs
  gemm_bt2<1><<<256, 256, 0, stream>>>(AY, BPW1, out, proj_b, 8, 1024, 1024);
}